// Round 6
// baseline (1424.391 us; speedup 1.0000x reference)
//
#include <hip/hip_runtime.h>
#include <hip/hip_bf16.h>
#include <hip/hip_fp16.h>

// LightGCN 3-hop propagation, 150k nodes, 4.8M edges, EMB=64.
// Round 12 (session R4, resubmitted R5 after GPU acquisition timeout):
//  - hop: persistent grid-stride waves (2048 blocks x 256thr = 32 waves/CU
//    resident; each wave loops ~18 rows) + __launch_bounds__(256,8).
//    R4 profile: occupancy 49% with VGPR=44 -> block-churn limited; depth-2
//    pipeline needs wave-parallelism to hide ~500cyc L3 gather latency.
//  - bin_kernel: EPB 8192->4096 (LDS 90KB->49KB -> 2 blocks/CU, was 1).
// R11 kept: unpredicated 16-edge chunks, depth-2 pipeline, single predicated
// tail. R9 kept: fp16 internal storage, packed int2 csr, fused epilogue.

#define NUM_USERS 100000
#define NUM_ITEMS 50000
#define N_NODES   150000
#define EMB       64
#define N_EDGES   4800000
#define NODE_ELEMS (N_NODES * EMB)   // 9,600,000
#define U_ELEMS    (NUM_USERS * EMB) // 6,400,000
#define I_ELEMS    (NUM_ITEMS * EMB) // 3,200,000

#define RPB 256                       // rows per bucket (2^8: row>>8, row&255)
#define NB  ((N_NODES + RPB - 1) / RPB)   // 586 buckets
#define EPB 4096                      // edges staged per bin block
#define EPW (EPB / 1024)              // edges per thread in bin_kernel

typedef __hip_bfloat16 bf16;

// flag bit0: float arrays are bf16 (else fp32). bit1: edge_index int64 (else int32).
__global__ void detect_kernel(const unsigned short* __restrict__ u16,
                              const int* __restrict__ ei32,
                              int* __restrict__ flag,
                              int* __restrict__ bucket_cnt)
{
    __shared__ int s_fp32, s_i32;
    if (threadIdx.x == 0) { s_fp32 = 0; s_i32 = 0; }
    __syncthreads();
    int t = threadIdx.x;
    for (int i = t; i < NB + 1; i += 256) bucket_cnt[i] = 0;
    unsigned short u = u16[t];
    int e = (u >> 7) & 0xFF;
    if (e >= 0xC0) atomicOr(&s_fp32, 1);
    if (t < 64 && ei32[2 * t + 1] != 0) atomicOr(&s_i32, 1);
    __syncthreads();
    if (t == 0) {
        int f = 0;
        if (!s_fp32) f |= 1;
        if (!s_i32)  f |= 2;
        *flag = f;
    }
}

__device__ __forceinline__ int load_row(const int* ei32, int f, size_t e) {
    return (f & 2) ? ei32[2 * e] : ei32[e];
}
__device__ __forceinline__ int load_col(const int* ei32, int f, size_t e) {
    return (f & 2) ? ei32[2 * ((size_t)N_EDGES + e)] : ei32[(size_t)N_EDGES + e];
}
__device__ __forceinline__ float load_w(const void* ew, int f, size_t e) {
    return (f & 1) ? __bfloat162float(((const bf16*)ew)[e]) : ((const float*)ew)[e];
}

// ---------- vectorized init: A (16-bit packed) + passthrough ----------
__global__ void init_vec_kernel(const void* __restrict__ users,
                                const void* __restrict__ items,
                                void* __restrict__ out,
                                void* __restrict__ A,
                                const int* __restrict__ flag)
{
    int g = blockIdx.x * blockDim.x + threadIdx.x;   // NODE_ELEMS/4 threads
    if (g >= NODE_ELEMS / 4) return;
    int g4 = g * 4;
    const bool isb = ((*flag) & 1);
    if (isb) {
        uint2 v;
        if (g4 < U_ELEMS) {
            v = ((const uint2*)users)[g];
            ((uint2*)((bf16*)out + U_ELEMS))[g] = v;
        } else {
            int ii = g - U_ELEMS / 4;
            v = ((const uint2*)items)[ii];
            ((uint2*)((bf16*)out + 2 * (size_t)U_ELEMS + I_ELEMS))[ii] = v;
        }
        ((uint2*)A)[g] = v;            // A stored bf16
    } else {
        float4 v;
        if (g4 < U_ELEMS) {
            v = ((const float4*)users)[g];
            ((float4*)((float*)out + U_ELEMS))[g] = v;
        } else {
            int ii = g - U_ELEMS / 4;
            v = ((const float4*)items)[ii];
            ((float4*)((float*)out + 2 * (size_t)U_ELEMS + I_ELEMS))[ii] = v;
        }
        __half2 ha = __floats2half2_rn(v.x, v.y);
        __half2 hb = __floats2half2_rn(v.z, v.w);
        uint2 u2;
        u2.x = *reinterpret_cast<unsigned int*>(&ha);
        u2.y = *reinterpret_cast<unsigned int*>(&hb);
        ((uint2*)A)[g] = u2;           // A stored fp16 (intermediates 16-bit)
    }
}

// ---------- binned CSR build ----------

__global__ void bucket_hist_kernel(const int* __restrict__ ei32,
                                   int* __restrict__ bucket_cnt,
                                   const int* __restrict__ flag)
{
    __shared__ int h[NB];
    for (int i = threadIdx.x; i < NB; i += blockDim.x) h[i] = 0;
    __syncthreads();
    const int f = *flag;
    const size_t stride = (size_t)gridDim.x * blockDim.x;
    for (size_t e = (size_t)blockIdx.x * blockDim.x + threadIdx.x; e < N_EDGES; e += stride)
        atomicAdd(&h[load_row(ei32, f, e) >> 8], 1);
    __syncthreads();
    for (int i = threadIdx.x; i < NB; i += blockDim.x)
        if (h[i]) atomicAdd(&bucket_cnt[i], h[i]);
}

__global__ void bucket_scan_kernel(const int* __restrict__ bucket_cnt,
                                   int* __restrict__ bucket_base,
                                   int* __restrict__ bucket_off)
{
    __shared__ int ls[16];
    const int t = threadIdx.x;           // 1024 threads, NB <= 1024
    const int lane = t & 63, wv = t >> 6;
    int x = (t < NB) ? bucket_cnt[t] : 0;
    int v = x;
    #pragma unroll
    for (int d = 1; d < 64; d <<= 1) { int y = __shfl_up(v, d, 64); if (lane >= d) v += y; }
    if (lane == 63) ls[wv] = v;
    __syncthreads();
    if (wv == 0 && lane < 16) {
        int s = ls[lane];
        #pragma unroll
        for (int d = 1; d < 16; d <<= 1) { int y = __shfl_up(s, d, 64); if (lane >= d) s += y; }
        ls[lane] = s;
    }
    __syncthreads();
    int waveoff = wv ? ls[wv - 1] : 0;
    int excl = waveoff + v - x;
    if (t < NB) { bucket_base[t] = excl; bucket_off[t] = excl; }
    if (t == 0) bucket_base[NB] = ls[15];   // == N_EDGES
}

// stage EPB edges in LDS, rank by bucket, write bucket-contiguous runs.
__global__ __launch_bounds__(1024) void bin_kernel(const int* __restrict__ ei32,
                                                   const void* __restrict__ ew,
                                                   int* __restrict__ bucket_off,
                                                   int2* __restrict__ rec,
                                                   const int* __restrict__ flag)
{
    __shared__ int2 stage[EPB];            // 32 KB
    __shared__ unsigned short bof[EPB];    // 8 KB
    __shared__ int hist[NB], excl0[NB], rank_[NB], gbase[NB];
    __shared__ int ls[16];
    const int t = threadIdx.x;
    const size_t base_e = (size_t)blockIdx.x * EPB;
    const int cnt = (int)(((base_e + EPB) <= N_EDGES) ? EPB : (N_EDGES - base_e));
    for (int i = t; i < NB; i += 1024) hist[i] = 0;
    __syncthreads();
    const int f = *flag;
    int  mybkt[EPW];
    int2 myrec[EPW];
    #pragma unroll
    for (int k = 0; k < EPW; ++k) {
        int idx = k * 1024 + t;
        if (idx < cnt) {
            size_t e = base_e + idx;
            int row = load_row(ei32, f, e);
            int col = load_col(ei32, f, e);
            float w = load_w(ew, f, e);
            mybkt[k] = row >> 8;
            myrec[k] = make_int2(col | ((row & 255) << 18), __float_as_int(w));
            atomicAdd(&hist[mybkt[k]], 1);
        } else mybkt[k] = -1;
    }
    __syncthreads();
    {   // scan hist[0..NB) -> excl0, rank_
        const int lane = t & 63, wv = t >> 6;
        int x = (t < NB) ? hist[t] : 0;
        int v = x;
        #pragma unroll
        for (int d = 1; d < 64; d <<= 1) { int y = __shfl_up(v, d, 64); if (lane >= d) v += y; }
        if (lane == 63) ls[wv] = v;
        __syncthreads();
        if (wv == 0 && lane < 16) {
            int s = ls[lane];
            #pragma unroll
            for (int d = 1; d < 16; d <<= 1) { int y = __shfl_up(s, d, 64); if (lane >= d) s += y; }
            ls[lane] = s;
        }
        __syncthreads();
        int waveoff = wv ? ls[wv - 1] : 0;
        int excl = waveoff + v - x;
        if (t < NB) { excl0[t] = excl; rank_[t] = excl; }
    }
    __syncthreads();
    if (t < NB && hist[t] > 0) gbase[t] = atomicAdd(&bucket_off[t], hist[t]);
    else if (t < NB)           gbase[t] = 0;
    #pragma unroll
    for (int k = 0; k < EPW; ++k) {
        if (mybkt[k] >= 0) {
            int p = atomicAdd(&rank_[mybkt[k]], 1);
            stage[p] = myrec[k];
            bof[p]   = (unsigned short)mybkt[k];
        }
    }
    __syncthreads();
    for (int s = t; s < cnt; s += 1024) {
        int b = bof[s];
        rec[gbase[b] + (s - excl0[b])] = stage[s];   // coalesced runs per bucket
    }
}

// one block per bucket: local row hist + scan -> rowptr; scatter packed
// (col,w) csr within an L2-resident window.
__global__ void local_fill_kernel(const int* __restrict__ bucket_base,
                                  const int2* __restrict__ rec,
                                  int2* __restrict__ csr,
                                  int* __restrict__ rowptr)
{
    __shared__ int hist[RPB], off[RPB], ls[4];
    const int b = blockIdx.x, t = threadIdx.x;      // 256 threads
    const int lo = bucket_base[b], hi = bucket_base[b + 1];
    const int rows = (N_NODES - b * RPB < RPB) ? (N_NODES - b * RPB) : RPB;
    hist[t] = 0;
    __syncthreads();
    for (int s = lo + t; s < hi; s += 256)
        atomicAdd(&hist[rec[s].x >> 18], 1);
    __syncthreads();
    const int lane = t & 63, wv = t >> 6;
    int x = hist[t];
    int v = x;
    #pragma unroll
    for (int d = 1; d < 64; d <<= 1) { int y = __shfl_up(v, d, 64); if (lane >= d) v += y; }
    if (lane == 63) ls[wv] = v;
    __syncthreads();
    if (wv == 0 && lane < 4) {
        int s = ls[lane];
        #pragma unroll
        for (int d = 1; d < 4; d <<= 1) { int y = __shfl_up(s, d, 64); if (lane >= d) s += y; }
        ls[lane] = s;
    }
    __syncthreads();
    int waveoff = wv ? ls[wv - 1] : 0;
    int excl = waveoff + v - x;
    if (t < rows) rowptr[b * RPB + t] = lo + excl;
    off[t] = lo + excl;
    if (b == NB - 1 && t == 0) rowptr[N_NODES] = N_EDGES;
    __syncthreads();
    for (int s = lo + t; s < hi; s += 256) {
        int2 r = rec[s];
        int rl = r.x >> 18;
        int pos = atomicAdd(&off[rl], 1);
        csr[pos] = make_int2(r.x & 0x3FFFF, r.y);   // packed (col, w-bits)
    }
}

// ---------- gather hop core ----------
// lanes 0-31 even edges, 32-63 odd edges; lane owns dims {2*hl, 2*hl+1} as
// one packed uint (bf16 or fp16). Main loop: unpredicated 16-edge chunks,
// depth-2 pipeline. Tail: ONE predicated 16-slot step (clamp to e-1, w=0).

template <bool ISB>
__device__ __forceinline__ void gather_row(const int2* __restrict__ csr,
                                           const unsigned int* __restrict__ p,
                                           int s, int e, int half, int hl,
                                           float& alo_o, float& ahi_o)
{
    float lo[4] = {0.f, 0.f, 0.f, 0.f};
    float hi[4] = {0.f, 0.f, 0.f, 0.f};
    const int len   = e - s;
    const int nfull = len >> 4;          // full 16-edge chunks
    const int rem   = len & 15;

    int2 cwA[8], cwB[8];
    unsigned int vA[8], vB[8];

#define LD_CSR(cw, base)                                             \
    _Pragma("unroll")                                                \
    for (int u = 0; u < 8; ++u) (cw)[u] = csr[(base) + 2 * u + half];
#define GATHER(v, cw)                                                \
    _Pragma("unroll")                                                \
    for (int u = 0; u < 8; ++u)                                      \
        (v)[u] = p[(size_t)((unsigned int)(cw)[u].x * 32u + hl)];
#define FMA8(cw, v)                                                  \
    _Pragma("unroll")                                                \
    for (int u = 0; u < 8; ++u) {                                    \
        float w = __int_as_float((cw)[u].y);                         \
        float fx, fy;                                                \
        if (ISB) {                                                   \
            fx = __uint_as_float((v)[u] << 16);                      \
            fy = __uint_as_float((v)[u] & 0xffff0000u);              \
        } else {                                                     \
            float2 f2 = __half22float2(                              \
                *reinterpret_cast<const __half2*>(&(v)[u]));         \
            fx = f2.x; fy = f2.y;                                    \
        }                                                            \
        lo[u & 3] = fmaf(w, fx, lo[u & 3]);                          \
        hi[u & 3] = fmaf(w, fy, hi[u & 3]);                          \
    }

    if (nfull > 0) {
        LD_CSR(cwA, s);
        if (nfull > 1) LD_CSR(cwB, s + 16);
        GATHER(vA, cwA);
        int c = 0;
        while (true) {
            // chunk c in A, chunk c+1 in B
            if (c + 1 < nfull) GATHER(vB, cwB);
            FMA8(cwA, vA);
            if (c + 1 >= nfull) break;
            if (c + 2 < nfull) LD_CSR(cwA, s + (c + 2) * 16);
            ++c;
            // chunk c in B, chunk c+1 in A
            if (c + 1 < nfull) GATHER(vA, cwA);
            FMA8(cwB, vB);
            if (c + 1 >= nfull) break;
            if (c + 2 < nfull) LD_CSR(cwB, s + (c + 2) * 16);
            ++c;
        }
    }
    if (rem) {
        const int base = s + nfull * 16;
        int2 cw[8];
        #pragma unroll
        for (int u = 0; u < 8; ++u) {
            int idx = base + 2 * u + half;
            int j = (idx < e) ? idx : (e - 1);
            cw[u] = csr[j];
            if (idx >= e) cw[u].y = 0;     // w = 0 for padding slots
        }
        unsigned int v[8];
        #pragma unroll
        for (int u = 0; u < 8; ++u)
            v[u] = p[(size_t)((unsigned int)cw[u].x * 32u + hl)];
        FMA8(cw, v);
    }
#undef LD_CSR
#undef GATHER
#undef FMA8
    alo_o = (lo[0] + lo[1]) + (lo[2] + lo[3]);
    ahi_o = (hi[0] + hi[1]) + (hi[2] + hi[3]);
}

#define HOP_BLOCKS 2048   // 8 blocks/CU; 8192 persistent waves grid-stride rows

// LAST fuses epilogue: out = (emb0 + h1 + h2 + h3)/4.
template <bool LAST>
__global__ __launch_bounds__(256, 8) void hop_kernel(
                           const int* __restrict__ rowptr,
                           const int2* __restrict__ csr,
                           const void* __restrict__ prev,
                           void* __restrict__ next,
                           const void* __restrict__ E0,   // emb0 (LAST only)
                           const void* __restrict__ H1,   // h1   (LAST only)
                           void* __restrict__ out,
                           const int* __restrict__ flag)
{
    const int half = (threadIdx.x >> 5) & 1;
    const int hl   = threadIdx.x & 31;
    const bool isb = ((*flag) & 1);
    const unsigned int* p = (const unsigned int*)prev;
    const int wid     = blockIdx.x * (blockDim.x >> 6) + (threadIdx.x >> 6);
    const int wstride = gridDim.x * (blockDim.x >> 6);

    for (int row = wid; row < N_NODES; row += wstride) {
        const int s = rowptr[row], e = rowptr[row + 1];
        float alo, ahi;
        if (isb) gather_row<true >(csr, p, s, e, half, hl, alo, ahi);
        else     gather_row<false>(csr, p, s, e, half, hl, alo, ahi);
        alo += __shfl_xor(alo, 32);      // combine even/odd edge halves
        ahi += __shfl_xor(ahi, 32);
        if (!half) {                     // half 0 writes the full row
            size_t o32 = (size_t)row * 32 + hl;  // 2-element units
            if (LAST) {
                size_t oo = o32 + ((row < NUM_USERS) ? 0 : (size_t)(U_ELEMS / 2));
                unsigned int e0u = ((const unsigned int*)E0)[o32];
                unsigned int h1u = ((const unsigned int*)H1)[o32];
                unsigned int h2u = ((const unsigned int*)prev)[o32];
                if (isb) {
                    float vlo = (__uint_as_float(e0u << 16) + __uint_as_float(h1u << 16) +
                                 __uint_as_float(h2u << 16) + alo) * 0.25f;
                    float vhi = (__uint_as_float(e0u & 0xffff0000u) + __uint_as_float(h1u & 0xffff0000u) +
                                 __uint_as_float(h2u & 0xffff0000u) + ahi) * 0.25f;
                    bf16 blo = __float2bfloat16(vlo), bhi = __float2bfloat16(vhi);
                    ((unsigned int*)out)[oo] =
                        ((unsigned int)(*reinterpret_cast<unsigned short*>(&bhi)) << 16) |
                        (*reinterpret_cast<unsigned short*>(&blo));
                } else {
                    float2 e0f = __half22float2(*reinterpret_cast<const __half2*>(&e0u));
                    float2 h1f = __half22float2(*reinterpret_cast<const __half2*>(&h1u));
                    float2 h2f = __half22float2(*reinterpret_cast<const __half2*>(&h2u));
                    float2 v;
                    v.x = (e0f.x + h1f.x + h2f.x + alo) * 0.25f;
                    v.y = (e0f.y + h1f.y + h2f.y + ahi) * 0.25f;
                    ((float2*)out)[oo] = v;
                }
            } else {
                if (isb) {
                    bf16 blo = __float2bfloat16(alo), bhi = __float2bfloat16(ahi);
                    ((unsigned int*)next)[o32] =
                        ((unsigned int)(*reinterpret_cast<unsigned short*>(&bhi)) << 16) |
                        (*reinterpret_cast<unsigned short*>(&blo));
                } else {
                    __half2 h = __floats2half2_rn(alo, ahi);
                    ((unsigned int*)next)[o32] = *reinterpret_cast<unsigned int*>(&h);
                }
            }
        }
    }
}

// ---------- R3 atomic fallback ----------

__global__ void init_kernel(const void* __restrict__ users,
                            const void* __restrict__ items,
                            void* __restrict__ out,
                            float* __restrict__ A,
                            float* __restrict__ B,
                            float* __restrict__ ACC,
                            const int* __restrict__ flag)
{
    int gid = blockIdx.x * blockDim.x + threadIdx.x;
    if (gid >= NODE_ELEMS) return;
    const bool isb = ((*flag) & 1);
    float v;
    if (gid < U_ELEMS) {
        if (isb) { bf16 b = ((const bf16*)users)[gid]; v = __bfloat162float(b); ((bf16*)out)[U_ELEMS + gid] = b; }
        else     { float fv = ((const float*)users)[gid]; v = fv; ((float*)out)[U_ELEMS + gid] = fv; }
    } else {
        int ii = gid - U_ELEMS;
        if (isb) { bf16 b = ((const bf16*)items)[ii]; v = __bfloat162float(b); ((bf16*)out)[2 * U_ELEMS + I_ELEMS + ii] = b; }
        else     { float fv = ((const float*)items)[ii]; v = fv; ((float*)out)[2 * U_ELEMS + I_ELEMS + ii] = fv; }
    }
    A[gid]   = v;
    B[gid]   = 0.0f;
    ACC[gid] = v;
}

__global__ void finalize_kernel(const float* __restrict__ acc,
                                void* __restrict__ out,
                                const int* __restrict__ flag)
{
    int gid = blockIdx.x * blockDim.x + threadIdx.x;
    if (gid >= NODE_ELEMS) return;
    const bool isb = ((*flag) & 1);
    float v = acc[gid] * 0.25f;
    size_t o = (gid < U_ELEMS) ? (size_t)gid : (size_t)(2 * U_ELEMS + (gid - U_ELEMS));
    if (isb) ((bf16*)out)[o]  = __float2bfloat16(v);
    else     ((float*)out)[o] = v;
}

__global__ void scatter_kernel(const int* __restrict__ ei32,
                               const void* __restrict__ ew,
                               const float* __restrict__ prev,
                               float* __restrict__ next,
                               const int* __restrict__ flag)
{
    int gid = blockIdx.x * blockDim.x + threadIdx.x;
    if (gid >= N_EDGES * 16) return;
    const int f = *flag;
    int e = gid >> 4;
    int j = (gid & 15) << 2;
    int row = load_row(ei32, f, e);
    int col = load_col(ei32, f, e);
    float w = load_w(ew, f, e);
    const float4 v = *reinterpret_cast<const float4*>(prev + (size_t)col * EMB + j);
    float* dst = next + (size_t)row * EMB + j;
    unsafeAtomicAdd(dst + 0, w * v.x);
    unsafeAtomicAdd(dst + 1, w * v.y);
    unsafeAtomicAdd(dst + 2, w * v.z);
    unsafeAtomicAdd(dst + 3, w * v.w);
}

__global__ void accum_zero_kernel(float* __restrict__ acc,
                                  const float* __restrict__ next,
                                  float* __restrict__ prevz)
{
    int gid = blockIdx.x * blockDim.x + threadIdx.x;
    if (gid >= NODE_ELEMS) return;
    acc[gid] += next[gid];
    prevz[gid] = 0.0f;
}

__global__ void sentinel_kernel(unsigned int* __restrict__ out, int nwords)
{
    int gid = blockIdx.x * blockDim.x + threadIdx.x;
    if (gid < nwords) out[gid] = 0x447A447Au;
}

extern "C" void kernel_launch(void* const* d_in, const int* in_sizes, int n_in,
                              void* d_out, int out_size, void* d_ws, size_t ws_size,
                              hipStream_t stream)
{
    const void* users = d_in[0];
    const void* items = d_in[1];
    const int*  ei32  = (const int*)d_in[2];
    const void* ew    = d_in[3];

    char* wsb  = (char*)d_ws;
    int*  flag = (int*)wsb;
    float* A   = (float*)(wsb + 256);              // fp32-sized; holds 16-bit in CSR path
    float* B   = A + (size_t)NODE_ELEMS;           // h1 buffer; aliases rec
    float* ACC = B + (size_t)NODE_ELEMS;           // h2 buffer in CSR path
    char* p    = (char*)(ACC + (size_t)NODE_ELEMS);
    int*  rowptr      = (int*)p;  p += (N_NODES + 4) * sizeof(int);
    int*  bucket_cnt  = (int*)p;  p += (NB + 2) * sizeof(int);
    int*  bucket_base = (int*)p;  p += (NB + 2) * sizeof(int);
    int*  bucket_off  = (int*)p;  p += (NB + 2) * sizeof(int);
    int2* csr         = (int2*)p; p += (size_t)N_EDGES * sizeof(int2);  // packed (col,w)
    int2* rec         = (int2*)B;                  // alias: dead before hop1 writes B

    const size_t need_csr    = (size_t)(p - wsb);                  // ~154.4 MB
    const size_t need_atomic = 256 + 3 * (size_t)NODE_ELEMS * sizeof(float);
    const int BLK = 256;
    const int node_blocks = (NODE_ELEMS + BLK - 1) / BLK;
    const int vec_blocks  = (NODE_ELEMS / 4 + BLK - 1) / BLK;
    const int bin_blocks  = (N_EDGES + EPB - 1) / EPB;   // 1172

    if (ws_size >= need_csr) {
        float* C = ACC;   // h2 buffer
        detect_kernel<<<1, BLK, 0, stream>>>((const unsigned short*)users, ei32, flag, bucket_cnt);
        init_vec_kernel<<<vec_blocks, BLK, 0, stream>>>(users, items, d_out, A, flag);
        bucket_hist_kernel<<<1024, BLK, 0, stream>>>(ei32, bucket_cnt, flag);
        bucket_scan_kernel<<<1, 1024, 0, stream>>>(bucket_cnt, bucket_base, bucket_off);
        bin_kernel<<<bin_blocks, 1024, 0, stream>>>(ei32, ew, bucket_off, rec, flag);
        local_fill_kernel<<<NB, RPB, 0, stream>>>(bucket_base, rec, csr, rowptr);

        // hop1: A(emb0) -> B(h1); hop2: B -> C(h2); hop3: C -> out, fusing
        // out = (A + B + C + h3)/4 in the epilogue.
        hop_kernel<false><<<HOP_BLOCKS, BLK, 0, stream>>>(rowptr, csr, A, B, nullptr, nullptr, nullptr, flag);
        hop_kernel<false><<<HOP_BLOCKS, BLK, 0, stream>>>(rowptr, csr, B, C, nullptr, nullptr, nullptr, flag);
        hop_kernel<true ><<<HOP_BLOCKS, BLK, 0, stream>>>(rowptr, csr, C, nullptr, A, B, d_out, flag);
    } else if (ws_size >= need_atomic) {
        const int sedge_blocks = (N_EDGES * 16 + BLK - 1) / BLK;
        detect_kernel<<<1, BLK, 0, stream>>>((const unsigned short*)users, ei32, flag, bucket_cnt);
        init_kernel<<<node_blocks, BLK, 0, stream>>>(users, items, d_out, A, B, ACC, flag);
        float* prev = A;
        float* nxt  = B;
        for (int h = 0; h < 3; ++h) {
            scatter_kernel<<<sedge_blocks, BLK, 0, stream>>>(ei32, ew, prev, nxt, flag);
            accum_zero_kernel<<<node_blocks, BLK, 0, stream>>>(ACC, nxt, prev);
            float* t = prev; prev = nxt; nxt = t;
        }
        finalize_kernel<<<node_blocks, BLK, 0, stream>>>(ACC, d_out, flag);
    } else {
        int nwords = out_size / 2;
        sentinel_kernel<<<(nwords + BLK - 1) / BLK, BLK, 0, stream>>>((unsigned int*)d_out, nwords);
    }
}

// Round 8
// 694.322 us; speedup vs baseline: 2.0515x; 2.0515x over previous
//
#include <hip/hip_runtime.h>
#include <hip/hip_bf16.h>
#include <hip/hip_fp16.h>

// LightGCN 3-hop propagation, 150k nodes, 4.8M edges, EMB=64.
// Round 13 (session R6, resubmitted R7 after GPU acquisition timeout):
//  - FIX R6 regression: __launch_bounds__(256,8) forced the register
//    allocator under ~64 VGPRs (occupancy tiers halve at 64/128/256) ->
//    VGPR=32 + full pipeline spill -> 1.0GB scratch writes/hop, 394us.
//    Now __launch_bounds__(256,4) (VGPR cap 128, kernel needs ~44-84):
//    persistent grid-stride shape kept, no spills.
//  - bin_kernel EPB=4096 kept (2 blocks/CU).
// R11 kept: unpredicated 16-edge chunks, depth-2 pipeline, single predicated
// tail. R9 kept: fp16 internal storage, packed int2 csr, fused epilogue.

#define NUM_USERS 100000
#define NUM_ITEMS 50000
#define N_NODES   150000
#define EMB       64
#define N_EDGES   4800000
#define NODE_ELEMS (N_NODES * EMB)   // 9,600,000
#define U_ELEMS    (NUM_USERS * EMB) // 6,400,000
#define I_ELEMS    (NUM_ITEMS * EMB) // 3,200,000

#define RPB 256                       // rows per bucket (2^8: row>>8, row&255)
#define NB  ((N_NODES + RPB - 1) / RPB)   // 586 buckets
#define EPB 4096                      // edges staged per bin block
#define EPW (EPB / 1024)              // edges per thread in bin_kernel

typedef __hip_bfloat16 bf16;

// flag bit0: float arrays are bf16 (else fp32). bit1: edge_index int64 (else int32).
__global__ void detect_kernel(const unsigned short* __restrict__ u16,
                              const int* __restrict__ ei32,
                              int* __restrict__ flag,
                              int* __restrict__ bucket_cnt)
{
    __shared__ int s_fp32, s_i32;
    if (threadIdx.x == 0) { s_fp32 = 0; s_i32 = 0; }
    __syncthreads();
    int t = threadIdx.x;
    for (int i = t; i < NB + 1; i += 256) bucket_cnt[i] = 0;
    unsigned short u = u16[t];
    int e = (u >> 7) & 0xFF;
    if (e >= 0xC0) atomicOr(&s_fp32, 1);
    if (t < 64 && ei32[2 * t + 1] != 0) atomicOr(&s_i32, 1);
    __syncthreads();
    if (t == 0) {
        int f = 0;
        if (!s_fp32) f |= 1;
        if (!s_i32)  f |= 2;
        *flag = f;
    }
}

__device__ __forceinline__ int load_row(const int* ei32, int f, size_t e) {
    return (f & 2) ? ei32[2 * e] : ei32[e];
}
__device__ __forceinline__ int load_col(const int* ei32, int f, size_t e) {
    return (f & 2) ? ei32[2 * ((size_t)N_EDGES + e)] : ei32[(size_t)N_EDGES + e];
}
__device__ __forceinline__ float load_w(const void* ew, int f, size_t e) {
    return (f & 1) ? __bfloat162float(((const bf16*)ew)[e]) : ((const float*)ew)[e];
}

// ---------- vectorized init: A (16-bit packed) + passthrough ----------
__global__ void init_vec_kernel(const void* __restrict__ users,
                                const void* __restrict__ items,
                                void* __restrict__ out,
                                void* __restrict__ A,
                                const int* __restrict__ flag)
{
    int g = blockIdx.x * blockDim.x + threadIdx.x;   // NODE_ELEMS/4 threads
    if (g >= NODE_ELEMS / 4) return;
    int g4 = g * 4;
    const bool isb = ((*flag) & 1);
    if (isb) {
        uint2 v;
        if (g4 < U_ELEMS) {
            v = ((const uint2*)users)[g];
            ((uint2*)((bf16*)out + U_ELEMS))[g] = v;
        } else {
            int ii = g - U_ELEMS / 4;
            v = ((const uint2*)items)[ii];
            ((uint2*)((bf16*)out + 2 * (size_t)U_ELEMS + I_ELEMS))[ii] = v;
        }
        ((uint2*)A)[g] = v;            // A stored bf16
    } else {
        float4 v;
        if (g4 < U_ELEMS) {
            v = ((const float4*)users)[g];
            ((float4*)((float*)out + U_ELEMS))[g] = v;
        } else {
            int ii = g - U_ELEMS / 4;
            v = ((const float4*)items)[ii];
            ((float4*)((float*)out + 2 * (size_t)U_ELEMS + I_ELEMS))[ii] = v;
        }
        __half2 ha = __floats2half2_rn(v.x, v.y);
        __half2 hb = __floats2half2_rn(v.z, v.w);
        uint2 u2;
        u2.x = *reinterpret_cast<unsigned int*>(&ha);
        u2.y = *reinterpret_cast<unsigned int*>(&hb);
        ((uint2*)A)[g] = u2;           // A stored fp16 (intermediates 16-bit)
    }
}

// ---------- binned CSR build ----------

__global__ void bucket_hist_kernel(const int* __restrict__ ei32,
                                   int* __restrict__ bucket_cnt,
                                   const int* __restrict__ flag)
{
    __shared__ int h[NB];
    for (int i = threadIdx.x; i < NB; i += blockDim.x) h[i] = 0;
    __syncthreads();
    const int f = *flag;
    const size_t stride = (size_t)gridDim.x * blockDim.x;
    for (size_t e = (size_t)blockIdx.x * blockDim.x + threadIdx.x; e < N_EDGES; e += stride)
        atomicAdd(&h[load_row(ei32, f, e) >> 8], 1);
    __syncthreads();
    for (int i = threadIdx.x; i < NB; i += blockDim.x)
        if (h[i]) atomicAdd(&bucket_cnt[i], h[i]);
}

__global__ void bucket_scan_kernel(const int* __restrict__ bucket_cnt,
                                   int* __restrict__ bucket_base,
                                   int* __restrict__ bucket_off)
{
    __shared__ int ls[16];
    const int t = threadIdx.x;           // 1024 threads, NB <= 1024
    const int lane = t & 63, wv = t >> 6;
    int x = (t < NB) ? bucket_cnt[t] : 0;
    int v = x;
    #pragma unroll
    for (int d = 1; d < 64; d <<= 1) { int y = __shfl_up(v, d, 64); if (lane >= d) v += y; }
    if (lane == 63) ls[wv] = v;
    __syncthreads();
    if (wv == 0 && lane < 16) {
        int s = ls[lane];
        #pragma unroll
        for (int d = 1; d < 16; d <<= 1) { int y = __shfl_up(s, d, 64); if (lane >= d) s += y; }
        ls[lane] = s;
    }
    __syncthreads();
    int waveoff = wv ? ls[wv - 1] : 0;
    int excl = waveoff + v - x;
    if (t < NB) { bucket_base[t] = excl; bucket_off[t] = excl; }
    if (t == 0) bucket_base[NB] = ls[15];   // == N_EDGES
}

// stage EPB edges in LDS, rank by bucket, write bucket-contiguous runs.
__global__ __launch_bounds__(1024) void bin_kernel(const int* __restrict__ ei32,
                                                   const void* __restrict__ ew,
                                                   int* __restrict__ bucket_off,
                                                   int2* __restrict__ rec,
                                                   const int* __restrict__ flag)
{
    __shared__ int2 stage[EPB];            // 32 KB
    __shared__ unsigned short bof[EPB];    // 8 KB
    __shared__ int hist[NB], excl0[NB], rank_[NB], gbase[NB];
    __shared__ int ls[16];
    const int t = threadIdx.x;
    const size_t base_e = (size_t)blockIdx.x * EPB;
    const int cnt = (int)(((base_e + EPB) <= N_EDGES) ? EPB : (N_EDGES - base_e));
    for (int i = t; i < NB; i += 1024) hist[i] = 0;
    __syncthreads();
    const int f = *flag;
    int  mybkt[EPW];
    int2 myrec[EPW];
    #pragma unroll
    for (int k = 0; k < EPW; ++k) {
        int idx = k * 1024 + t;
        if (idx < cnt) {
            size_t e = base_e + idx;
            int row = load_row(ei32, f, e);
            int col = load_col(ei32, f, e);
            float w = load_w(ew, f, e);
            mybkt[k] = row >> 8;
            myrec[k] = make_int2(col | ((row & 255) << 18), __float_as_int(w));
            atomicAdd(&hist[mybkt[k]], 1);
        } else mybkt[k] = -1;
    }
    __syncthreads();
    {   // scan hist[0..NB) -> excl0, rank_
        const int lane = t & 63, wv = t >> 6;
        int x = (t < NB) ? hist[t] : 0;
        int v = x;
        #pragma unroll
        for (int d = 1; d < 64; d <<= 1) { int y = __shfl_up(v, d, 64); if (lane >= d) v += y; }
        if (lane == 63) ls[wv] = v;
        __syncthreads();
        if (wv == 0 && lane < 16) {
            int s = ls[lane];
            #pragma unroll
            for (int d = 1; d < 16; d <<= 1) { int y = __shfl_up(s, d, 64); if (lane >= d) s += y; }
            ls[lane] = s;
        }
        __syncthreads();
        int waveoff = wv ? ls[wv - 1] : 0;
        int excl = waveoff + v - x;
        if (t < NB) { excl0[t] = excl; rank_[t] = excl; }
    }
    __syncthreads();
    if (t < NB && hist[t] > 0) gbase[t] = atomicAdd(&bucket_off[t], hist[t]);
    else if (t < NB)           gbase[t] = 0;
    #pragma unroll
    for (int k = 0; k < EPW; ++k) {
        if (mybkt[k] >= 0) {
            int p = atomicAdd(&rank_[mybkt[k]], 1);
            stage[p] = myrec[k];
            bof[p]   = (unsigned short)mybkt[k];
        }
    }
    __syncthreads();
    for (int s = t; s < cnt; s += 1024) {
        int b = bof[s];
        rec[gbase[b] + (s - excl0[b])] = stage[s];   // coalesced runs per bucket
    }
}

// one block per bucket: local row hist + scan -> rowptr; scatter packed
// (col,w) csr within an L2-resident window.
__global__ void local_fill_kernel(const int* __restrict__ bucket_base,
                                  const int2* __restrict__ rec,
                                  int2* __restrict__ csr,
                                  int* __restrict__ rowptr)
{
    __shared__ int hist[RPB], off[RPB], ls[4];
    const int b = blockIdx.x, t = threadIdx.x;      // 256 threads
    const int lo = bucket_base[b], hi = bucket_base[b + 1];
    const int rows = (N_NODES - b * RPB < RPB) ? (N_NODES - b * RPB) : RPB;
    hist[t] = 0;
    __syncthreads();
    for (int s = lo + t; s < hi; s += 256)
        atomicAdd(&hist[rec[s].x >> 18], 1);
    __syncthreads();
    const int lane = t & 63, wv = t >> 6;
    int x = hist[t];
    int v = x;
    #pragma unroll
    for (int d = 1; d < 64; d <<= 1) { int y = __shfl_up(v, d, 64); if (lane >= d) v += y; }
    if (lane == 63) ls[wv] = v;
    __syncthreads();
    if (wv == 0 && lane < 4) {
        int s = ls[lane];
        #pragma unroll
        for (int d = 1; d < 4; d <<= 1) { int y = __shfl_up(s, d, 64); if (lane >= d) s += y; }
        ls[lane] = s;
    }
    __syncthreads();
    int waveoff = wv ? ls[wv - 1] : 0;
    int excl = waveoff + v - x;
    if (t < rows) rowptr[b * RPB + t] = lo + excl;
    off[t] = lo + excl;
    if (b == NB - 1 && t == 0) rowptr[N_NODES] = N_EDGES;
    __syncthreads();
    for (int s = lo + t; s < hi; s += 256) {
        int2 r = rec[s];
        int rl = r.x >> 18;
        int pos = atomicAdd(&off[rl], 1);
        csr[pos] = make_int2(r.x & 0x3FFFF, r.y);   // packed (col, w-bits)
    }
}

// ---------- gather hop core ----------
// lanes 0-31 even edges, 32-63 odd edges; lane owns dims {2*hl, 2*hl+1} as
// one packed uint (bf16 or fp16). Main loop: unpredicated 16-edge chunks,
// depth-2 pipeline. Tail: ONE predicated 16-slot step (clamp to e-1, w=0).

template <bool ISB>
__device__ __forceinline__ void gather_row(const int2* __restrict__ csr,
                                           const unsigned int* __restrict__ p,
                                           int s, int e, int half, int hl,
                                           float& alo_o, float& ahi_o)
{
    float lo[4] = {0.f, 0.f, 0.f, 0.f};
    float hi[4] = {0.f, 0.f, 0.f, 0.f};
    const int len   = e - s;
    const int nfull = len >> 4;          // full 16-edge chunks
    const int rem   = len & 15;

    int2 cwA[8], cwB[8];
    unsigned int vA[8], vB[8];

#define LD_CSR(cw, base)                                             \
    _Pragma("unroll")                                                \
    for (int u = 0; u < 8; ++u) (cw)[u] = csr[(base) + 2 * u + half];
#define GATHER(v, cw)                                                \
    _Pragma("unroll")                                                \
    for (int u = 0; u < 8; ++u)                                      \
        (v)[u] = p[(size_t)((unsigned int)(cw)[u].x * 32u + hl)];
#define FMA8(cw, v)                                                  \
    _Pragma("unroll")                                                \
    for (int u = 0; u < 8; ++u) {                                    \
        float w = __int_as_float((cw)[u].y);                         \
        float fx, fy;                                                \
        if (ISB) {                                                   \
            fx = __uint_as_float((v)[u] << 16);                      \
            fy = __uint_as_float((v)[u] & 0xffff0000u);              \
        } else {                                                     \
            float2 f2 = __half22float2(                              \
                *reinterpret_cast<const __half2*>(&(v)[u]));         \
            fx = f2.x; fy = f2.y;                                    \
        }                                                            \
        lo[u & 3] = fmaf(w, fx, lo[u & 3]);                          \
        hi[u & 3] = fmaf(w, fy, hi[u & 3]);                          \
    }

    if (nfull > 0) {
        LD_CSR(cwA, s);
        if (nfull > 1) LD_CSR(cwB, s + 16);
        GATHER(vA, cwA);
        int c = 0;
        while (true) {
            // chunk c in A, chunk c+1 in B
            if (c + 1 < nfull) GATHER(vB, cwB);
            FMA8(cwA, vA);
            if (c + 1 >= nfull) break;
            if (c + 2 < nfull) LD_CSR(cwA, s + (c + 2) * 16);
            ++c;
            // chunk c in B, chunk c+1 in A
            if (c + 1 < nfull) GATHER(vA, cwA);
            FMA8(cwB, vB);
            if (c + 1 >= nfull) break;
            if (c + 2 < nfull) LD_CSR(cwB, s + (c + 2) * 16);
            ++c;
        }
    }
    if (rem) {
        const int base = s + nfull * 16;
        int2 cw[8];
        #pragma unroll
        for (int u = 0; u < 8; ++u) {
            int idx = base + 2 * u + half;
            int j = (idx < e) ? idx : (e - 1);
            cw[u] = csr[j];
            if (idx >= e) cw[u].y = 0;     // w = 0 for padding slots
        }
        unsigned int v[8];
        #pragma unroll
        for (int u = 0; u < 8; ++u)
            v[u] = p[(size_t)((unsigned int)cw[u].x * 32u + hl)];
        FMA8(cw, v);
    }
#undef LD_CSR
#undef GATHER
#undef FMA8
    alo_o = (lo[0] + lo[1]) + (lo[2] + lo[3]);
    ahi_o = (hi[0] + hi[1]) + (hi[2] + hi[3]);
}

#define HOP_BLOCKS 2048   // persistent waves grid-stride rows

// LAST fuses epilogue: out = (emb0 + h1 + h2 + h3)/4.
template <bool LAST>
__global__ __launch_bounds__(256, 4) void hop_kernel(
                           const int* __restrict__ rowptr,
                           const int2* __restrict__ csr,
                           const void* __restrict__ prev,
                           void* __restrict__ next,
                           const void* __restrict__ E0,   // emb0 (LAST only)
                           const void* __restrict__ H1,   // h1   (LAST only)
                           void* __restrict__ out,
                           const int* __restrict__ flag)
{
    const int half = (threadIdx.x >> 5) & 1;
    const int hl   = threadIdx.x & 31;
    const bool isb = ((*flag) & 1);
    const unsigned int* p = (const unsigned int*)prev;
    const int wid     = blockIdx.x * (blockDim.x >> 6) + (threadIdx.x >> 6);
    const int wstride = gridDim.x * (blockDim.x >> 6);

    for (int row = wid; row < N_NODES; row += wstride) {
        const int s = rowptr[row], e = rowptr[row + 1];
        float alo, ahi;
        if (isb) gather_row<true >(csr, p, s, e, half, hl, alo, ahi);
        else     gather_row<false>(csr, p, s, e, half, hl, alo, ahi);
        alo += __shfl_xor(alo, 32);      // combine even/odd edge halves
        ahi += __shfl_xor(ahi, 32);
        if (!half) {                     // half 0 writes the full row
            size_t o32 = (size_t)row * 32 + hl;  // 2-element units
            if (LAST) {
                size_t oo = o32 + ((row < NUM_USERS) ? 0 : (size_t)(U_ELEMS / 2));
                unsigned int e0u = ((const unsigned int*)E0)[o32];
                unsigned int h1u = ((const unsigned int*)H1)[o32];
                unsigned int h2u = ((const unsigned int*)prev)[o32];
                if (isb) {
                    float vlo = (__uint_as_float(e0u << 16) + __uint_as_float(h1u << 16) +
                                 __uint_as_float(h2u << 16) + alo) * 0.25f;
                    float vhi = (__uint_as_float(e0u & 0xffff0000u) + __uint_as_float(h1u & 0xffff0000u) +
                                 __uint_as_float(h2u & 0xffff0000u) + ahi) * 0.25f;
                    bf16 blo = __float2bfloat16(vlo), bhi = __float2bfloat16(vhi);
                    ((unsigned int*)out)[oo] =
                        ((unsigned int)(*reinterpret_cast<unsigned short*>(&bhi)) << 16) |
                        (*reinterpret_cast<unsigned short*>(&blo));
                } else {
                    float2 e0f = __half22float2(*reinterpret_cast<const __half2*>(&e0u));
                    float2 h1f = __half22float2(*reinterpret_cast<const __half2*>(&h1u));
                    float2 h2f = __half22float2(*reinterpret_cast<const __half2*>(&h2u));
                    float2 v;
                    v.x = (e0f.x + h1f.x + h2f.x + alo) * 0.25f;
                    v.y = (e0f.y + h1f.y + h2f.y + ahi) * 0.25f;
                    ((float2*)out)[oo] = v;
                }
            } else {
                if (isb) {
                    bf16 blo = __float2bfloat16(alo), bhi = __float2bfloat16(ahi);
                    ((unsigned int*)next)[o32] =
                        ((unsigned int)(*reinterpret_cast<unsigned short*>(&bhi)) << 16) |
                        (*reinterpret_cast<unsigned short*>(&blo));
                } else {
                    __half2 h = __floats2half2_rn(alo, ahi);
                    ((unsigned int*)next)[o32] = *reinterpret_cast<unsigned int*>(&h);
                }
            }
        }
    }
}

// ---------- R3 atomic fallback ----------

__global__ void init_kernel(const void* __restrict__ users,
                            const void* __restrict__ items,
                            void* __restrict__ out,
                            float* __restrict__ A,
                            float* __restrict__ B,
                            float* __restrict__ ACC,
                            const int* __restrict__ flag)
{
    int gid = blockIdx.x * blockDim.x + threadIdx.x;
    if (gid >= NODE_ELEMS) return;
    const bool isb = ((*flag) & 1);
    float v;
    if (gid < U_ELEMS) {
        if (isb) { bf16 b = ((const bf16*)users)[gid]; v = __bfloat162float(b); ((bf16*)out)[U_ELEMS + gid] = b; }
        else     { float fv = ((const float*)users)[gid]; v = fv; ((float*)out)[U_ELEMS + gid] = fv; }
    } else {
        int ii = gid - U_ELEMS;
        if (isb) { bf16 b = ((const bf16*)items)[ii]; v = __bfloat162float(b); ((bf16*)out)[2 * U_ELEMS + I_ELEMS + ii] = b; }
        else     { float fv = ((const float*)items)[ii]; v = fv; ((float*)out)[2 * U_ELEMS + I_ELEMS + ii] = fv; }
    }
    A[gid]   = v;
    B[gid]   = 0.0f;
    ACC[gid] = v;
}

__global__ void finalize_kernel(const float* __restrict__ acc,
                                void* __restrict__ out,
                                const int* __restrict__ flag)
{
    int gid = blockIdx.x * blockDim.x + threadIdx.x;
    if (gid >= NODE_ELEMS) return;
    const bool isb = ((*flag) & 1);
    float v = acc[gid] * 0.25f;
    size_t o = (gid < U_ELEMS) ? (size_t)gid : (size_t)(2 * U_ELEMS + (gid - U_ELEMS));
    if (isb) ((bf16*)out)[o]  = __float2bfloat16(v);
    else     ((float*)out)[o] = v;
}

__global__ void scatter_kernel(const int* __restrict__ ei32,
                               const void* __restrict__ ew,
                               const float* __restrict__ prev,
                               float* __restrict__ next,
                               const int* __restrict__ flag)
{
    int gid = blockIdx.x * blockDim.x + threadIdx.x;
    if (gid >= N_EDGES * 16) return;
    const int f = *flag;
    int e = gid >> 4;
    int j = (gid & 15) << 2;
    int row = load_row(ei32, f, e);
    int col = load_col(ei32, f, e);
    float w = load_w(ew, f, e);
    const float4 v = *reinterpret_cast<const float4*>(prev + (size_t)col * EMB + j);
    float* dst = next + (size_t)row * EMB + j;
    unsafeAtomicAdd(dst + 0, w * v.x);
    unsafeAtomicAdd(dst + 1, w * v.y);
    unsafeAtomicAdd(dst + 2, w * v.z);
    unsafeAtomicAdd(dst + 3, w * v.w);
}

__global__ void accum_zero_kernel(float* __restrict__ acc,
                                  const float* __restrict__ next,
                                  float* __restrict__ prevz)
{
    int gid = blockIdx.x * blockDim.x + threadIdx.x;
    if (gid >= NODE_ELEMS) return;
    acc[gid] += next[gid];
    prevz[gid] = 0.0f;
}

__global__ void sentinel_kernel(unsigned int* __restrict__ out, int nwords)
{
    int gid = blockIdx.x * blockDim.x + threadIdx.x;
    if (gid < nwords) out[gid] = 0x447A447Au;
}

extern "C" void kernel_launch(void* const* d_in, const int* in_sizes, int n_in,
                              void* d_out, int out_size, void* d_ws, size_t ws_size,
                              hipStream_t stream)
{
    const void* users = d_in[0];
    const void* items = d_in[1];
    const int*  ei32  = (const int*)d_in[2];
    const void* ew    = d_in[3];

    char* wsb  = (char*)d_ws;
    int*  flag = (int*)wsb;
    float* A   = (float*)(wsb + 256);              // fp32-sized; holds 16-bit in CSR path
    float* B   = A + (size_t)NODE_ELEMS;           // h1 buffer; aliases rec
    float* ACC = B + (size_t)NODE_ELEMS;           // h2 buffer in CSR path
    char* p    = (char*)(ACC + (size_t)NODE_ELEMS);
    int*  rowptr      = (int*)p;  p += (N_NODES + 4) * sizeof(int);
    int*  bucket_cnt  = (int*)p;  p += (NB + 2) * sizeof(int);
    int*  bucket_base = (int*)p;  p += (NB + 2) * sizeof(int);
    int*  bucket_off  = (int*)p;  p += (NB + 2) * sizeof(int);
    int2* csr         = (int2*)p; p += (size_t)N_EDGES * sizeof(int2);  // packed (col,w)
    int2* rec         = (int2*)B;                  // alias: dead before hop1 writes B

    const size_t need_csr    = (size_t)(p - wsb);                  // ~154.4 MB
    const size_t need_atomic = 256 + 3 * (size_t)NODE_ELEMS * sizeof(float);
    const int BLK = 256;
    const int node_blocks = (NODE_ELEMS + BLK - 1) / BLK;
    const int vec_blocks  = (NODE_ELEMS / 4 + BLK - 1) / BLK;
    const int bin_blocks  = (N_EDGES + EPB - 1) / EPB;   // 1172

    if (ws_size >= need_csr) {
        float* C = ACC;   // h2 buffer
        detect_kernel<<<1, BLK, 0, stream>>>((const unsigned short*)users, ei32, flag, bucket_cnt);
        init_vec_kernel<<<vec_blocks, BLK, 0, stream>>>(users, items, d_out, A, flag);
        bucket_hist_kernel<<<1024, BLK, 0, stream>>>(ei32, bucket_cnt, flag);
        bucket_scan_kernel<<<1, 1024, 0, stream>>>(bucket_cnt, bucket_base, bucket_off);
        bin_kernel<<<bin_blocks, 1024, 0, stream>>>(ei32, ew, bucket_off, rec, flag);
        local_fill_kernel<<<NB, RPB, 0, stream>>>(bucket_base, rec, csr, rowptr);

        // hop1: A(emb0) -> B(h1); hop2: B -> C(h2); hop3: C -> out, fusing
        // out = (A + B + C + h3)/4 in the epilogue.
        hop_kernel<false><<<HOP_BLOCKS, BLK, 0, stream>>>(rowptr, csr, A, B, nullptr, nullptr, nullptr, flag);
        hop_kernel<false><<<HOP_BLOCKS, BLK, 0, stream>>>(rowptr, csr, B, C, nullptr, nullptr, nullptr, flag);
        hop_kernel<true ><<<HOP_BLOCKS, BLK, 0, stream>>>(rowptr, csr, C, nullptr, A, B, d_out, flag);
    } else if (ws_size >= need_atomic) {
        const int sedge_blocks = (N_EDGES * 16 + BLK - 1) / BLK;
        detect_kernel<<<1, BLK, 0, stream>>>((const unsigned short*)users, ei32, flag, bucket_cnt);
        init_kernel<<<node_blocks, BLK, 0, stream>>>(users, items, d_out, A, B, ACC, flag);
        float* prev = A;
        float* nxt  = B;
        for (int h = 0; h < 3; ++h) {
            scatter_kernel<<<sedge_blocks, BLK, 0, stream>>>(ei32, ew, prev, nxt, flag);
            accum_zero_kernel<<<node_blocks, BLK, 0, stream>>>(ACC, nxt, prev);
            float* t = prev; prev = nxt; nxt = t;
        }
        finalize_kernel<<<node_blocks, BLK, 0, stream>>>(ACC, d_out, flag);
    } else {
        int nwords = out_size / 2;
        sentinel_kernel<<<(nwords + BLK - 1) / BLK, BLK, 0, stream>>>((unsigned int*)d_out, nwords);
    }
}

// Round 9
// 577.485 us; speedup vs baseline: 2.4665x; 1.2023x over previous
//
#include <hip/hip_runtime.h>
#include <hip/hip_bf16.h>
#include <hip/hip_fp16.h>

// LightGCN 3-hop propagation, 150k nodes, 4.8M edges, EMB=64.
// Round 14 (session R8):
//  - REVERT persistent waves (R8 profile: occupancy 42% < R4's 49%, hop
//    154.7 vs 139.6 -> churn theory refuted). Back to per-row launch,
//    no launch_bounds (R4 best-measured config).
//  - hop gather widened: uint2 per lane (16 lanes/row, 4 edges per gather
//    instruction, 4 dims/lane). Same bytes + same cache lines, HALF the
//    VMEM instructions -> discriminates issue-width-bound vs
//    request-throughput-bound (time flat => request wall).
// R11 kept: 16-edge chunks, depth-2 pipeline, single predicated tail.
// R9 kept: fp16 internal storage, packed int2 csr, fused epilogue.

#define NUM_USERS 100000
#define NUM_ITEMS 50000
#define N_NODES   150000
#define EMB       64
#define N_EDGES   4800000
#define NODE_ELEMS (N_NODES * EMB)   // 9,600,000
#define U_ELEMS    (NUM_USERS * EMB) // 6,400,000
#define I_ELEMS    (NUM_ITEMS * EMB) // 3,200,000

#define RPB 256                       // rows per bucket (2^8: row>>8, row&255)
#define NB  ((N_NODES + RPB - 1) / RPB)   // 586 buckets
#define EPB 4096                      // edges staged per bin block
#define EPW (EPB / 1024)              // edges per thread in bin_kernel

typedef __hip_bfloat16 bf16;

__device__ __forceinline__ unsigned int pack_bf16(float a, float b) {
    bf16 x = __float2bfloat16(a), y = __float2bfloat16(b);
    return ((unsigned int)(*reinterpret_cast<unsigned short*>(&y)) << 16) |
           (*reinterpret_cast<unsigned short*>(&x));
}

// flag bit0: float arrays are bf16 (else fp32). bit1: edge_index int64 (else int32).
__global__ void detect_kernel(const unsigned short* __restrict__ u16,
                              const int* __restrict__ ei32,
                              int* __restrict__ flag,
                              int* __restrict__ bucket_cnt)
{
    __shared__ int s_fp32, s_i32;
    if (threadIdx.x == 0) { s_fp32 = 0; s_i32 = 0; }
    __syncthreads();
    int t = threadIdx.x;
    for (int i = t; i < NB + 1; i += 256) bucket_cnt[i] = 0;
    unsigned short u = u16[t];
    int e = (u >> 7) & 0xFF;
    if (e >= 0xC0) atomicOr(&s_fp32, 1);
    if (t < 64 && ei32[2 * t + 1] != 0) atomicOr(&s_i32, 1);
    __syncthreads();
    if (t == 0) {
        int f = 0;
        if (!s_fp32) f |= 1;
        if (!s_i32)  f |= 2;
        *flag = f;
    }
}

__device__ __forceinline__ int load_row(const int* ei32, int f, size_t e) {
    return (f & 2) ? ei32[2 * e] : ei32[e];
}
__device__ __forceinline__ int load_col(const int* ei32, int f, size_t e) {
    return (f & 2) ? ei32[2 * ((size_t)N_EDGES + e)] : ei32[(size_t)N_EDGES + e];
}
__device__ __forceinline__ float load_w(const void* ew, int f, size_t e) {
    return (f & 1) ? __bfloat162float(((const bf16*)ew)[e]) : ((const float*)ew)[e];
}

// ---------- vectorized init: A (16-bit packed) + passthrough ----------
__global__ void init_vec_kernel(const void* __restrict__ users,
                                const void* __restrict__ items,
                                void* __restrict__ out,
                                void* __restrict__ A,
                                const int* __restrict__ flag)
{
    int g = blockIdx.x * blockDim.x + threadIdx.x;   // NODE_ELEMS/4 threads
    if (g >= NODE_ELEMS / 4) return;
    int g4 = g * 4;
    const bool isb = ((*flag) & 1);
    if (isb) {
        uint2 v;
        if (g4 < U_ELEMS) {
            v = ((const uint2*)users)[g];
            ((uint2*)((bf16*)out + U_ELEMS))[g] = v;
        } else {
            int ii = g - U_ELEMS / 4;
            v = ((const uint2*)items)[ii];
            ((uint2*)((bf16*)out + 2 * (size_t)U_ELEMS + I_ELEMS))[ii] = v;
        }
        ((uint2*)A)[g] = v;            // A stored bf16
    } else {
        float4 v;
        if (g4 < U_ELEMS) {
            v = ((const float4*)users)[g];
            ((float4*)((float*)out + U_ELEMS))[g] = v;
        } else {
            int ii = g - U_ELEMS / 4;
            v = ((const float4*)items)[ii];
            ((float4*)((float*)out + 2 * (size_t)U_ELEMS + I_ELEMS))[ii] = v;
        }
        __half2 ha = __floats2half2_rn(v.x, v.y);
        __half2 hb = __floats2half2_rn(v.z, v.w);
        uint2 u2;
        u2.x = *reinterpret_cast<unsigned int*>(&ha);
        u2.y = *reinterpret_cast<unsigned int*>(&hb);
        ((uint2*)A)[g] = u2;           // A stored fp16 (intermediates 16-bit)
    }
}

// ---------- binned CSR build ----------

__global__ void bucket_hist_kernel(const int* __restrict__ ei32,
                                   int* __restrict__ bucket_cnt,
                                   const int* __restrict__ flag)
{
    __shared__ int h[NB];
    for (int i = threadIdx.x; i < NB; i += blockDim.x) h[i] = 0;
    __syncthreads();
    const int f = *flag;
    const size_t stride = (size_t)gridDim.x * blockDim.x;
    for (size_t e = (size_t)blockIdx.x * blockDim.x + threadIdx.x; e < N_EDGES; e += stride)
        atomicAdd(&h[load_row(ei32, f, e) >> 8], 1);
    __syncthreads();
    for (int i = threadIdx.x; i < NB; i += blockDim.x)
        if (h[i]) atomicAdd(&bucket_cnt[i], h[i]);
}

__global__ void bucket_scan_kernel(const int* __restrict__ bucket_cnt,
                                   int* __restrict__ bucket_base,
                                   int* __restrict__ bucket_off)
{
    __shared__ int ls[16];
    const int t = threadIdx.x;           // 1024 threads, NB <= 1024
    const int lane = t & 63, wv = t >> 6;
    int x = (t < NB) ? bucket_cnt[t] : 0;
    int v = x;
    #pragma unroll
    for (int d = 1; d < 64; d <<= 1) { int y = __shfl_up(v, d, 64); if (lane >= d) v += y; }
    if (lane == 63) ls[wv] = v;
    __syncthreads();
    if (wv == 0 && lane < 16) {
        int s = ls[lane];
        #pragma unroll
        for (int d = 1; d < 16; d <<= 1) { int y = __shfl_up(s, d, 64); if (lane >= d) s += y; }
        ls[lane] = s;
    }
    __syncthreads();
    int waveoff = wv ? ls[wv - 1] : 0;
    int excl = waveoff + v - x;
    if (t < NB) { bucket_base[t] = excl; bucket_off[t] = excl; }
    if (t == 0) bucket_base[NB] = ls[15];   // == N_EDGES
}

// stage EPB edges in LDS, rank by bucket, write bucket-contiguous runs.
__global__ __launch_bounds__(1024) void bin_kernel(const int* __restrict__ ei32,
                                                   const void* __restrict__ ew,
                                                   int* __restrict__ bucket_off,
                                                   int2* __restrict__ rec,
                                                   const int* __restrict__ flag)
{
    __shared__ int2 stage[EPB];            // 32 KB
    __shared__ unsigned short bof[EPB];    // 8 KB
    __shared__ int hist[NB], excl0[NB], rank_[NB], gbase[NB];
    __shared__ int ls[16];
    const int t = threadIdx.x;
    const size_t base_e = (size_t)blockIdx.x * EPB;
    const int cnt = (int)(((base_e + EPB) <= N_EDGES) ? EPB : (N_EDGES - base_e));
    for (int i = t; i < NB; i += 1024) hist[i] = 0;
    __syncthreads();
    const int f = *flag;
    int  mybkt[EPW];
    int2 myrec[EPW];
    #pragma unroll
    for (int k = 0; k < EPW; ++k) {
        int idx = k * 1024 + t;
        if (idx < cnt) {
            size_t e = base_e + idx;
            int row = load_row(ei32, f, e);
            int col = load_col(ei32, f, e);
            float w = load_w(ew, f, e);
            mybkt[k] = row >> 8;
            myrec[k] = make_int2(col | ((row & 255) << 18), __float_as_int(w));
            atomicAdd(&hist[mybkt[k]], 1);
        } else mybkt[k] = -1;
    }
    __syncthreads();
    {   // scan hist[0..NB) -> excl0, rank_
        const int lane = t & 63, wv = t >> 6;
        int x = (t < NB) ? hist[t] : 0;
        int v = x;
        #pragma unroll
        for (int d = 1; d < 64; d <<= 1) { int y = __shfl_up(v, d, 64); if (lane >= d) v += y; }
        if (lane == 63) ls[wv] = v;
        __syncthreads();
        if (wv == 0 && lane < 16) {
            int s = ls[lane];
            #pragma unroll
            for (int d = 1; d < 16; d <<= 1) { int y = __shfl_up(s, d, 64); if (lane >= d) s += y; }
            ls[lane] = s;
        }
        __syncthreads();
        int waveoff = wv ? ls[wv - 1] : 0;
        int excl = waveoff + v - x;
        if (t < NB) { excl0[t] = excl; rank_[t] = excl; }
    }
    __syncthreads();
    if (t < NB && hist[t] > 0) gbase[t] = atomicAdd(&bucket_off[t], hist[t]);
    else if (t < NB)           gbase[t] = 0;
    #pragma unroll
    for (int k = 0; k < EPW; ++k) {
        if (mybkt[k] >= 0) {
            int p = atomicAdd(&rank_[mybkt[k]], 1);
            stage[p] = myrec[k];
            bof[p]   = (unsigned short)mybkt[k];
        }
    }
    __syncthreads();
    for (int s = t; s < cnt; s += 1024) {
        int b = bof[s];
        rec[gbase[b] + (s - excl0[b])] = stage[s];   // coalesced runs per bucket
    }
}

// one block per bucket: local row hist + scan -> rowptr; scatter packed
// (col,w) csr within an L2-resident window.
__global__ void local_fill_kernel(const int* __restrict__ bucket_base,
                                  const int2* __restrict__ rec,
                                  int2* __restrict__ csr,
                                  int* __restrict__ rowptr)
{
    __shared__ int hist[RPB], off[RPB], ls[4];
    const int b = blockIdx.x, t = threadIdx.x;      // 256 threads
    const int lo = bucket_base[b], hi = bucket_base[b + 1];
    const int rows = (N_NODES - b * RPB < RPB) ? (N_NODES - b * RPB) : RPB;
    hist[t] = 0;
    __syncthreads();
    for (int s = lo + t; s < hi; s += 256)
        atomicAdd(&hist[rec[s].x >> 18], 1);
    __syncthreads();
    const int lane = t & 63, wv = t >> 6;
    int x = hist[t];
    int v = x;
    #pragma unroll
    for (int d = 1; d < 64; d <<= 1) { int y = __shfl_up(v, d, 64); if (lane >= d) v += y; }
    if (lane == 63) ls[wv] = v;
    __syncthreads();
    if (wv == 0 && lane < 4) {
        int s = ls[lane];
        #pragma unroll
        for (int d = 1; d < 4; d <<= 1) { int y = __shfl_up(s, d, 64); if (lane >= d) s += y; }
        ls[lane] = s;
    }
    __syncthreads();
    int waveoff = wv ? ls[wv - 1] : 0;
    int excl = waveoff + v - x;
    if (t < rows) rowptr[b * RPB + t] = lo + excl;
    off[t] = lo + excl;
    if (b == NB - 1 && t == 0) rowptr[N_NODES] = N_EDGES;
    __syncthreads();
    for (int s = lo + t; s < hi; s += 256) {
        int2 r = rec[s];
        int rl = r.x >> 18;
        int pos = atomicAdd(&off[rl], 1);
        csr[pos] = make_int2(r.x & 0x3FFFF, r.y);   // packed (col, w-bits)
    }
}

// ---------- gather hop core: uint2 gathers ----------
// Lane q=(tid>>4)&3 owns edge-slot q of each 4-edge step; hl=tid&15 owns
// dims {4hl..4hl+3} as one uint2 (4 x 16-bit). 16-edge chunks = 4 steps.
// Main loop: depth-2 pipeline. Tail: ONE predicated 16-slot step.

template <bool ISB>
__device__ __forceinline__ void gather_row4(const int2* __restrict__ csr,
                                            const uint2* __restrict__ p,
                                            int s, int e, int q, int hl,
                                            float f[4])
{
    const int len   = e - s;
    const int nfull = len >> 4;          // full 16-edge chunks
    const int rem   = len & 15;

    int2 cwA[4], cwB[4];
    uint2 vA[4], vB[4];

#define LD_CSR(cw, base)                                             \
    _Pragma("unroll")                                                \
    for (int u = 0; u < 4; ++u) (cw)[u] = csr[(base) + 4 * u + q];
#define GATHER(v, cw)                                                \
    _Pragma("unroll")                                                \
    for (int u = 0; u < 4; ++u)                                      \
        (v)[u] = p[(size_t)((unsigned int)(cw)[u].x * 16u + hl)];
#define FMA4(cw, v)                                                  \
    _Pragma("unroll")                                                \
    for (int u = 0; u < 4; ++u) {                                    \
        float w = __int_as_float((cw)[u].y);                         \
        float d0, d1, d2, d3;                                        \
        if (ISB) {                                                   \
            d0 = __uint_as_float((v)[u].x << 16);                    \
            d1 = __uint_as_float((v)[u].x & 0xffff0000u);            \
            d2 = __uint_as_float((v)[u].y << 16);                    \
            d3 = __uint_as_float((v)[u].y & 0xffff0000u);            \
        } else {                                                     \
            float2 fa = __half22float2(                              \
                *reinterpret_cast<const __half2*>(&(v)[u].x));       \
            float2 fb = __half22float2(                              \
                *reinterpret_cast<const __half2*>(&(v)[u].y));       \
            d0 = fa.x; d1 = fa.y; d2 = fb.x; d3 = fb.y;              \
        }                                                            \
        f[0] = fmaf(w, d0, f[0]);                                    \
        f[1] = fmaf(w, d1, f[1]);                                    \
        f[2] = fmaf(w, d2, f[2]);                                    \
        f[3] = fmaf(w, d3, f[3]);                                    \
    }

    if (nfull > 0) {
        LD_CSR(cwA, s);
        if (nfull > 1) LD_CSR(cwB, s + 16);
        GATHER(vA, cwA);
        int c = 0;
        while (true) {
            // chunk c in A, chunk c+1 in B
            if (c + 1 < nfull) GATHER(vB, cwB);
            FMA4(cwA, vA);
            if (c + 1 >= nfull) break;
            if (c + 2 < nfull) LD_CSR(cwA, s + (c + 2) * 16);
            ++c;
            // chunk c in B, chunk c+1 in A
            if (c + 1 < nfull) GATHER(vA, cwA);
            FMA4(cwB, vB);
            if (c + 1 >= nfull) break;
            if (c + 2 < nfull) LD_CSR(cwB, s + (c + 2) * 16);
            ++c;
        }
    }
    if (rem) {
        const int base = s + nfull * 16;
        int2 cw[4];
        #pragma unroll
        for (int u = 0; u < 4; ++u) {
            int idx = base + 4 * u + q;
            int j = (idx < e) ? idx : (e - 1);
            cw[u] = csr[j];
            if (idx >= e) cw[u].y = 0;     // w = 0 for padding slots
        }
        uint2 v[4];
        #pragma unroll
        for (int u = 0; u < 4; ++u)
            v[u] = p[(size_t)((unsigned int)cw[u].x * 16u + hl)];
        FMA4(cw, v);
    }
#undef LD_CSR
#undef GATHER
#undef FMA4
}

// LAST fuses epilogue: out = (emb0 + h1 + h2 + h3)/4.
template <bool LAST>
__global__ void hop_kernel(const int* __restrict__ rowptr,
                           const int2* __restrict__ csr,
                           const void* __restrict__ prev,
                           void* __restrict__ next,
                           const void* __restrict__ E0,   // emb0 (LAST only)
                           const void* __restrict__ H1,   // h1   (LAST only)
                           void* __restrict__ out,
                           const int* __restrict__ flag)
{
    int row = blockIdx.x * (blockDim.x >> 6) + (threadIdx.x >> 6);
    if (row >= N_NODES) return;
    const int q  = (threadIdx.x >> 4) & 3;
    const int hl = threadIdx.x & 15;
    const bool isb = ((*flag) & 1);
    const int s = rowptr[row], e = rowptr[row + 1];
    const uint2* p = (const uint2*)prev;
    float f[4] = {0.f, 0.f, 0.f, 0.f};
    if (isb) gather_row4<true >(csr, p, s, e, q, hl, f);
    else     gather_row4<false>(csr, p, s, e, q, hl, f);
    #pragma unroll
    for (int k = 0; k < 4; ++k) {        // combine the 4 edge-slot quarters
        f[k] += __shfl_xor(f[k], 16);
        f[k] += __shfl_xor(f[k], 32);
    }
    if ((threadIdx.x & 48) != 0) return; // quarter-0 lanes write the row
    size_t o8 = (size_t)row * 16 + hl;   // 4-element (8-byte) units
    if (LAST) {
        size_t oo = o8 + ((row < NUM_USERS) ? 0 : (size_t)(U_ELEMS / 4));
        uint2 e0u = ((const uint2*)E0)[o8];
        uint2 h1u = ((const uint2*)H1)[o8];
        uint2 h2u = ((const uint2*)prev)[o8];
        float v0, v1, v2, v3;
        if (isb) {
            v0 = (__uint_as_float(e0u.x << 16) + __uint_as_float(h1u.x << 16) +
                  __uint_as_float(h2u.x << 16) + f[0]) * 0.25f;
            v1 = (__uint_as_float(e0u.x & 0xffff0000u) + __uint_as_float(h1u.x & 0xffff0000u) +
                  __uint_as_float(h2u.x & 0xffff0000u) + f[1]) * 0.25f;
            v2 = (__uint_as_float(e0u.y << 16) + __uint_as_float(h1u.y << 16) +
                  __uint_as_float(h2u.y << 16) + f[2]) * 0.25f;
            v3 = (__uint_as_float(e0u.y & 0xffff0000u) + __uint_as_float(h1u.y & 0xffff0000u) +
                  __uint_as_float(h2u.y & 0xffff0000u) + f[3]) * 0.25f;
            uint2 o;
            o.x = pack_bf16(v0, v1);
            o.y = pack_bf16(v2, v3);
            ((uint2*)out)[oo] = o;
        } else {
            float2 e0a = __half22float2(*reinterpret_cast<const __half2*>(&e0u.x));
            float2 e0b = __half22float2(*reinterpret_cast<const __half2*>(&e0u.y));
            float2 h1a = __half22float2(*reinterpret_cast<const __half2*>(&h1u.x));
            float2 h1b = __half22float2(*reinterpret_cast<const __half2*>(&h1u.y));
            float2 h2a = __half22float2(*reinterpret_cast<const __half2*>(&h2u.x));
            float2 h2b = __half22float2(*reinterpret_cast<const __half2*>(&h2u.y));
            float4 v;
            v.x = (e0a.x + h1a.x + h2a.x + f[0]) * 0.25f;
            v.y = (e0a.y + h1a.y + h2a.y + f[1]) * 0.25f;
            v.z = (e0b.x + h1b.x + h2b.x + f[2]) * 0.25f;
            v.w = (e0b.y + h1b.y + h2b.y + f[3]) * 0.25f;
            ((float4*)out)[oo] = v;
        }
    } else {
        uint2 o;
        if (isb) {
            o.x = pack_bf16(f[0], f[1]);
            o.y = pack_bf16(f[2], f[3]);
        } else {
            __half2 ha = __floats2half2_rn(f[0], f[1]);
            __half2 hb = __floats2half2_rn(f[2], f[3]);
            o.x = *reinterpret_cast<unsigned int*>(&ha);
            o.y = *reinterpret_cast<unsigned int*>(&hb);
        }
        ((uint2*)next)[o8] = o;
    }
}

// ---------- R3 atomic fallback ----------

__global__ void init_kernel(const void* __restrict__ users,
                            const void* __restrict__ items,
                            void* __restrict__ out,
                            float* __restrict__ A,
                            float* __restrict__ B,
                            float* __restrict__ ACC,
                            const int* __restrict__ flag)
{
    int gid = blockIdx.x * blockDim.x + threadIdx.x;
    if (gid >= NODE_ELEMS) return;
    const bool isb = ((*flag) & 1);
    float v;
    if (gid < U_ELEMS) {
        if (isb) { bf16 b = ((const bf16*)users)[gid]; v = __bfloat162float(b); ((bf16*)out)[U_ELEMS + gid] = b; }
        else     { float fv = ((const float*)users)[gid]; v = fv; ((float*)out)[U_ELEMS + gid] = fv; }
    } else {
        int ii = gid - U_ELEMS;
        if (isb) { bf16 b = ((const bf16*)items)[ii]; v = __bfloat162float(b); ((bf16*)out)[2 * U_ELEMS + I_ELEMS + ii] = b; }
        else     { float fv = ((const float*)items)[ii]; v = fv; ((float*)out)[2 * U_ELEMS + I_ELEMS + ii] = fv; }
    }
    A[gid]   = v;
    B[gid]   = 0.0f;
    ACC[gid] = v;
}

__global__ void finalize_kernel(const float* __restrict__ acc,
                                void* __restrict__ out,
                                const int* __restrict__ flag)
{
    int gid = blockIdx.x * blockDim.x + threadIdx.x;
    if (gid >= NODE_ELEMS) return;
    const bool isb = ((*flag) & 1);
    float v = acc[gid] * 0.25f;
    size_t o = (gid < U_ELEMS) ? (size_t)gid : (size_t)(2 * U_ELEMS + (gid - U_ELEMS));
    if (isb) ((bf16*)out)[o]  = __float2bfloat16(v);
    else     ((float*)out)[o] = v;
}

__global__ void scatter_kernel(const int* __restrict__ ei32,
                               const void* __restrict__ ew,
                               const float* __restrict__ prev,
                               float* __restrict__ next,
                               const int* __restrict__ flag)
{
    int gid = blockIdx.x * blockDim.x + threadIdx.x;
    if (gid >= N_EDGES * 16) return;
    const int f = *flag;
    int e = gid >> 4;
    int j = (gid & 15) << 2;
    int row = load_row(ei32, f, e);
    int col = load_col(ei32, f, e);
    float w = load_w(ew, f, e);
    const float4 v = *reinterpret_cast<const float4*>(prev + (size_t)col * EMB + j);
    float* dst = next + (size_t)row * EMB + j;
    unsafeAtomicAdd(dst + 0, w * v.x);
    unsafeAtomicAdd(dst + 1, w * v.y);
    unsafeAtomicAdd(dst + 2, w * v.z);
    unsafeAtomicAdd(dst + 3, w * v.w);
}

__global__ void accum_zero_kernel(float* __restrict__ acc,
                                  const float* __restrict__ next,
                                  float* __restrict__ prevz)
{
    int gid = blockIdx.x * blockDim.x + threadIdx.x;
    if (gid >= NODE_ELEMS) return;
    acc[gid] += next[gid];
    prevz[gid] = 0.0f;
}

__global__ void sentinel_kernel(unsigned int* __restrict__ out, int nwords)
{
    int gid = blockIdx.x * blockDim.x + threadIdx.x;
    if (gid < nwords) out[gid] = 0x447A447Au;
}

extern "C" void kernel_launch(void* const* d_in, const int* in_sizes, int n_in,
                              void* d_out, int out_size, void* d_ws, size_t ws_size,
                              hipStream_t stream)
{
    const void* users = d_in[0];
    const void* items = d_in[1];
    const int*  ei32  = (const int*)d_in[2];
    const void* ew    = d_in[3];

    char* wsb  = (char*)d_ws;
    int*  flag = (int*)wsb;
    float* A   = (float*)(wsb + 256);              // fp32-sized; holds 16-bit in CSR path
    float* B   = A + (size_t)NODE_ELEMS;           // h1 buffer; aliases rec
    float* ACC = B + (size_t)NODE_ELEMS;           // h2 buffer in CSR path
    char* p    = (char*)(ACC + (size_t)NODE_ELEMS);
    int*  rowptr      = (int*)p;  p += (N_NODES + 4) * sizeof(int);
    int*  bucket_cnt  = (int*)p;  p += (NB + 2) * sizeof(int);
    int*  bucket_base = (int*)p;  p += (NB + 2) * sizeof(int);
    int*  bucket_off  = (int*)p;  p += (NB + 2) * sizeof(int);
    int2* csr         = (int2*)p; p += (size_t)N_EDGES * sizeof(int2);  // packed (col,w)
    int2* rec         = (int2*)B;                  // alias: dead before hop1 writes B

    const size_t need_csr    = (size_t)(p - wsb);                  // ~154.4 MB
    const size_t need_atomic = 256 + 3 * (size_t)NODE_ELEMS * sizeof(float);
    const int BLK = 256;
    const int node_blocks = (NODE_ELEMS + BLK - 1) / BLK;
    const int vec_blocks  = (NODE_ELEMS / 4 + BLK - 1) / BLK;
    const int row_blocks  = (N_NODES + 3) / 4;       // 4 rows (waves) per block
    const int bin_blocks  = (N_EDGES + EPB - 1) / EPB;   // 1172

    if (ws_size >= need_csr) {
        float* C = ACC;   // h2 buffer
        detect_kernel<<<1, BLK, 0, stream>>>((const unsigned short*)users, ei32, flag, bucket_cnt);
        init_vec_kernel<<<vec_blocks, BLK, 0, stream>>>(users, items, d_out, A, flag);
        bucket_hist_kernel<<<1024, BLK, 0, stream>>>(ei32, bucket_cnt, flag);
        bucket_scan_kernel<<<1, 1024, 0, stream>>>(bucket_cnt, bucket_base, bucket_off);
        bin_kernel<<<bin_blocks, 1024, 0, stream>>>(ei32, ew, bucket_off, rec, flag);
        local_fill_kernel<<<NB, RPB, 0, stream>>>(bucket_base, rec, csr, rowptr);

        // hop1: A(emb0) -> B(h1); hop2: B -> C(h2); hop3: C -> out, fusing
        // out = (A + B + C + h3)/4 in the epilogue.
        hop_kernel<false><<<row_blocks, BLK, 0, stream>>>(rowptr, csr, A, B, nullptr, nullptr, nullptr, flag);
        hop_kernel<false><<<row_blocks, BLK, 0, stream>>>(rowptr, csr, B, C, nullptr, nullptr, nullptr, flag);
        hop_kernel<true ><<<row_blocks, BLK, 0, stream>>>(rowptr, csr, C, nullptr, A, B, d_out, flag);
    } else if (ws_size >= need_atomic) {
        const int sedge_blocks = (N_EDGES * 16 + BLK - 1) / BLK;
        detect_kernel<<<1, BLK, 0, stream>>>((const unsigned short*)users, ei32, flag, bucket_cnt);
        init_kernel<<<node_blocks, BLK, 0, stream>>>(users, items, d_out, A, B, ACC, flag);
        float* prev = A;
        float* nxt  = B;
        for (int h = 0; h < 3; ++h) {
            scatter_kernel<<<sedge_blocks, BLK, 0, stream>>>(ei32, ew, prev, nxt, flag);
            accum_zero_kernel<<<node_blocks, BLK, 0, stream>>>(ACC, nxt, prev);
            float* t = prev; prev = nxt; nxt = t;
        }
        finalize_kernel<<<node_blocks, BLK, 0, stream>>>(ACC, d_out, flag);
    } else {
        int nwords = out_size / 2;
        sentinel_kernel<<<(nwords + BLK - 1) / BLK, BLK, 0, stream>>>((unsigned int*)d_out, nwords);
    }
}

// Round 10
// 536.975 us; speedup vs baseline: 2.6526x; 1.0754x over previous
//
#include <hip/hip_runtime.h>
#include <hip/hip_bf16.h>
#include <hip/hip_fp16.h>

// LightGCN 3-hop propagation, 150k nodes, 4.8M edges, EMB=64.
// Round 15 (session R9):
//  - hop gather widened again: uint4 per lane (8 lanes/row, 8 edges per
//    gather instruction, 8 dims/lane). R9 confirmed issue-width-bound
//    (uint->uint2 gave 139.6->115.2us at constant FETCH); this halves the
//    VMEM instruction count once more. Reduction: 24 shfl_xor/row (8,16,32).
//    Flat time => L2-miss request wall reached; next target is build phase.
// R14 kept: per-row launch (no launch_bounds), EPB 4096.
// R11 kept: 16-edge chunks, depth-2 pipeline, single predicated tail.
// R9 kept: fp16 internal storage, packed int2 csr, fused epilogue.

#define NUM_USERS 100000
#define NUM_ITEMS 50000
#define N_NODES   150000
#define EMB       64
#define N_EDGES   4800000
#define NODE_ELEMS (N_NODES * EMB)   // 9,600,000
#define U_ELEMS    (NUM_USERS * EMB) // 6,400,000
#define I_ELEMS    (NUM_ITEMS * EMB) // 3,200,000

#define RPB 256                       // rows per bucket (2^8: row>>8, row&255)
#define NB  ((N_NODES + RPB - 1) / RPB)   // 586 buckets
#define EPB 4096                      // edges staged per bin block
#define EPW (EPB / 1024)              // edges per thread in bin_kernel

typedef __hip_bfloat16 bf16;

__device__ __forceinline__ unsigned int pack_bf16(float a, float b) {
    bf16 x = __float2bfloat16(a), y = __float2bfloat16(b);
    return ((unsigned int)(*reinterpret_cast<unsigned short*>(&y)) << 16) |
           (*reinterpret_cast<unsigned short*>(&x));
}
__device__ __forceinline__ float bf_lo(unsigned int u) { return __uint_as_float(u << 16); }
__device__ __forceinline__ float bf_hi(unsigned int u) { return __uint_as_float(u & 0xffff0000u); }
__device__ __forceinline__ float2 h2f(unsigned int u) {
    return __half22float2(*reinterpret_cast<const __half2*>(&u));
}

// flag bit0: float arrays are bf16 (else fp32). bit1: edge_index int64 (else int32).
__global__ void detect_kernel(const unsigned short* __restrict__ u16,
                              const int* __restrict__ ei32,
                              int* __restrict__ flag,
                              int* __restrict__ bucket_cnt)
{
    __shared__ int s_fp32, s_i32;
    if (threadIdx.x == 0) { s_fp32 = 0; s_i32 = 0; }
    __syncthreads();
    int t = threadIdx.x;
    for (int i = t; i < NB + 1; i += 256) bucket_cnt[i] = 0;
    unsigned short u = u16[t];
    int e = (u >> 7) & 0xFF;
    if (e >= 0xC0) atomicOr(&s_fp32, 1);
    if (t < 64 && ei32[2 * t + 1] != 0) atomicOr(&s_i32, 1);
    __syncthreads();
    if (t == 0) {
        int f = 0;
        if (!s_fp32) f |= 1;
        if (!s_i32)  f |= 2;
        *flag = f;
    }
}

__device__ __forceinline__ int load_row(const int* ei32, int f, size_t e) {
    return (f & 2) ? ei32[2 * e] : ei32[e];
}
__device__ __forceinline__ int load_col(const int* ei32, int f, size_t e) {
    return (f & 2) ? ei32[2 * ((size_t)N_EDGES + e)] : ei32[(size_t)N_EDGES + e];
}
__device__ __forceinline__ float load_w(const void* ew, int f, size_t e) {
    return (f & 1) ? __bfloat162float(((const bf16*)ew)[e]) : ((const float*)ew)[e];
}

// ---------- vectorized init: A (16-bit packed) + passthrough ----------
__global__ void init_vec_kernel(const void* __restrict__ users,
                                const void* __restrict__ items,
                                void* __restrict__ out,
                                void* __restrict__ A,
                                const int* __restrict__ flag)
{
    int g = blockIdx.x * blockDim.x + threadIdx.x;   // NODE_ELEMS/4 threads
    if (g >= NODE_ELEMS / 4) return;
    int g4 = g * 4;
    const bool isb = ((*flag) & 1);
    if (isb) {
        uint2 v;
        if (g4 < U_ELEMS) {
            v = ((const uint2*)users)[g];
            ((uint2*)((bf16*)out + U_ELEMS))[g] = v;
        } else {
            int ii = g - U_ELEMS / 4;
            v = ((const uint2*)items)[ii];
            ((uint2*)((bf16*)out + 2 * (size_t)U_ELEMS + I_ELEMS))[ii] = v;
        }
        ((uint2*)A)[g] = v;            // A stored bf16
    } else {
        float4 v;
        if (g4 < U_ELEMS) {
            v = ((const float4*)users)[g];
            ((float4*)((float*)out + U_ELEMS))[g] = v;
        } else {
            int ii = g - U_ELEMS / 4;
            v = ((const float4*)items)[ii];
            ((float4*)((float*)out + 2 * (size_t)U_ELEMS + I_ELEMS))[ii] = v;
        }
        __half2 ha = __floats2half2_rn(v.x, v.y);
        __half2 hb = __floats2half2_rn(v.z, v.w);
        uint2 u2;
        u2.x = *reinterpret_cast<unsigned int*>(&ha);
        u2.y = *reinterpret_cast<unsigned int*>(&hb);
        ((uint2*)A)[g] = u2;           // A stored fp16 (intermediates 16-bit)
    }
}

// ---------- binned CSR build ----------

__global__ void bucket_hist_kernel(const int* __restrict__ ei32,
                                   int* __restrict__ bucket_cnt,
                                   const int* __restrict__ flag)
{
    __shared__ int h[NB];
    for (int i = threadIdx.x; i < NB; i += blockDim.x) h[i] = 0;
    __syncthreads();
    const int f = *flag;
    const size_t stride = (size_t)gridDim.x * blockDim.x;
    for (size_t e = (size_t)blockIdx.x * blockDim.x + threadIdx.x; e < N_EDGES; e += stride)
        atomicAdd(&h[load_row(ei32, f, e) >> 8], 1);
    __syncthreads();
    for (int i = threadIdx.x; i < NB; i += blockDim.x)
        if (h[i]) atomicAdd(&bucket_cnt[i], h[i]);
}

__global__ void bucket_scan_kernel(const int* __restrict__ bucket_cnt,
                                   int* __restrict__ bucket_base,
                                   int* __restrict__ bucket_off)
{
    __shared__ int ls[16];
    const int t = threadIdx.x;           // 1024 threads, NB <= 1024
    const int lane = t & 63, wv = t >> 6;
    int x = (t < NB) ? bucket_cnt[t] : 0;
    int v = x;
    #pragma unroll
    for (int d = 1; d < 64; d <<= 1) { int y = __shfl_up(v, d, 64); if (lane >= d) v += y; }
    if (lane == 63) ls[wv] = v;
    __syncthreads();
    if (wv == 0 && lane < 16) {
        int s = ls[lane];
        #pragma unroll
        for (int d = 1; d < 16; d <<= 1) { int y = __shfl_up(s, d, 64); if (lane >= d) s += y; }
        ls[lane] = s;
    }
    __syncthreads();
    int waveoff = wv ? ls[wv - 1] : 0;
    int excl = waveoff + v - x;
    if (t < NB) { bucket_base[t] = excl; bucket_off[t] = excl; }
    if (t == 0) bucket_base[NB] = ls[15];   // == N_EDGES
}

// stage EPB edges in LDS, rank by bucket, write bucket-contiguous runs.
__global__ __launch_bounds__(1024) void bin_kernel(const int* __restrict__ ei32,
                                                   const void* __restrict__ ew,
                                                   int* __restrict__ bucket_off,
                                                   int2* __restrict__ rec,
                                                   const int* __restrict__ flag)
{
    __shared__ int2 stage[EPB];            // 32 KB
    __shared__ unsigned short bof[EPB];    // 8 KB
    __shared__ int hist[NB], excl0[NB], rank_[NB], gbase[NB];
    __shared__ int ls[16];
    const int t = threadIdx.x;
    const size_t base_e = (size_t)blockIdx.x * EPB;
    const int cnt = (int)(((base_e + EPB) <= N_EDGES) ? EPB : (N_EDGES - base_e));
    for (int i = t; i < NB; i += 1024) hist[i] = 0;
    __syncthreads();
    const int f = *flag;
    int  mybkt[EPW];
    int2 myrec[EPW];
    #pragma unroll
    for (int k = 0; k < EPW; ++k) {
        int idx = k * 1024 + t;
        if (idx < cnt) {
            size_t e = base_e + idx;
            int row = load_row(ei32, f, e);
            int col = load_col(ei32, f, e);
            float w = load_w(ew, f, e);
            mybkt[k] = row >> 8;
            myrec[k] = make_int2(col | ((row & 255) << 18), __float_as_int(w));
            atomicAdd(&hist[mybkt[k]], 1);
        } else mybkt[k] = -1;
    }
    __syncthreads();
    {   // scan hist[0..NB) -> excl0, rank_
        const int lane = t & 63, wv = t >> 6;
        int x = (t < NB) ? hist[t] : 0;
        int v = x;
        #pragma unroll
        for (int d = 1; d < 64; d <<= 1) { int y = __shfl_up(v, d, 64); if (lane >= d) v += y; }
        if (lane == 63) ls[wv] = v;
        __syncthreads();
        if (wv == 0 && lane < 16) {
            int s = ls[lane];
            #pragma unroll
            for (int d = 1; d < 16; d <<= 1) { int y = __shfl_up(s, d, 64); if (lane >= d) s += y; }
            ls[lane] = s;
        }
        __syncthreads();
        int waveoff = wv ? ls[wv - 1] : 0;
        int excl = waveoff + v - x;
        if (t < NB) { excl0[t] = excl; rank_[t] = excl; }
    }
    __syncthreads();
    if (t < NB && hist[t] > 0) gbase[t] = atomicAdd(&bucket_off[t], hist[t]);
    else if (t < NB)           gbase[t] = 0;
    #pragma unroll
    for (int k = 0; k < EPW; ++k) {
        if (mybkt[k] >= 0) {
            int p = atomicAdd(&rank_[mybkt[k]], 1);
            stage[p] = myrec[k];
            bof[p]   = (unsigned short)mybkt[k];
        }
    }
    __syncthreads();
    for (int s = t; s < cnt; s += 1024) {
        int b = bof[s];
        rec[gbase[b] + (s - excl0[b])] = stage[s];   // coalesced runs per bucket
    }
}

// one block per bucket: local row hist + scan -> rowptr; scatter packed
// (col,w) csr within an L2-resident window.
__global__ void local_fill_kernel(const int* __restrict__ bucket_base,
                                  const int2* __restrict__ rec,
                                  int2* __restrict__ csr,
                                  int* __restrict__ rowptr)
{
    __shared__ int hist[RPB], off[RPB], ls[4];
    const int b = blockIdx.x, t = threadIdx.x;      // 256 threads
    const int lo = bucket_base[b], hi = bucket_base[b + 1];
    const int rows = (N_NODES - b * RPB < RPB) ? (N_NODES - b * RPB) : RPB;
    hist[t] = 0;
    __syncthreads();
    for (int s = lo + t; s < hi; s += 256)
        atomicAdd(&hist[rec[s].x >> 18], 1);
    __syncthreads();
    const int lane = t & 63, wv = t >> 6;
    int x = hist[t];
    int v = x;
    #pragma unroll
    for (int d = 1; d < 64; d <<= 1) { int y = __shfl_up(v, d, 64); if (lane >= d) v += y; }
    if (lane == 63) ls[wv] = v;
    __syncthreads();
    if (wv == 0 && lane < 4) {
        int s = ls[lane];
        #pragma unroll
        for (int d = 1; d < 4; d <<= 1) { int y = __shfl_up(s, d, 64); if (lane >= d) s += y; }
        ls[lane] = s;
    }
    __syncthreads();
    int waveoff = wv ? ls[wv - 1] : 0;
    int excl = waveoff + v - x;
    if (t < rows) rowptr[b * RPB + t] = lo + excl;
    off[t] = lo + excl;
    if (b == NB - 1 && t == 0) rowptr[N_NODES] = N_EDGES;
    __syncthreads();
    for (int s = lo + t; s < hi; s += 256) {
        int2 r = rec[s];
        int rl = r.x >> 18;
        int pos = atomicAdd(&off[rl], 1);
        csr[pos] = make_int2(r.x & 0x3FFFF, r.y);   // packed (col, w-bits)
    }
}

// ---------- gather hop core: uint4 gathers ----------
// Lane q=(tid>>3)&7 owns edge-slot q of each 8-edge step; hl=tid&7 owns
// dims {8hl..8hl+7} as one uint4 (8 x 16-bit). 16-edge chunk = 2 steps.
// Main loop: depth-2 pipeline. Tail: ONE predicated 16-slot step.

template <bool ISB>
__device__ __forceinline__ void gather_row8(const int2* __restrict__ csr,
                                            const uint4* __restrict__ p,
                                            int s, int e, int q, int hl,
                                            float f[8])
{
    const int len   = e - s;
    const int nfull = len >> 4;          // full 16-edge chunks
    const int rem   = len & 15;

    int2 cwA[2], cwB[2];
    uint4 vA[2], vB[2];

#define LD_CSR(cw, base)                                             \
    _Pragma("unroll")                                                \
    for (int u = 0; u < 2; ++u) (cw)[u] = csr[(base) + 8 * u + q];
#define GATHER(v, cw)                                                \
    _Pragma("unroll")                                                \
    for (int u = 0; u < 2; ++u)                                      \
        (v)[u] = p[(size_t)((unsigned int)(cw)[u].x * 8u + hl)];
#define FMA2(cw, v)                                                  \
    _Pragma("unroll")                                                \
    for (int u = 0; u < 2; ++u) {                                    \
        float w = __int_as_float((cw)[u].y);                         \
        float d0, d1, d2, d3, d4, d5, d6, d7;                        \
        if (ISB) {                                                   \
            d0 = bf_lo((v)[u].x); d1 = bf_hi((v)[u].x);              \
            d2 = bf_lo((v)[u].y); d3 = bf_hi((v)[u].y);              \
            d4 = bf_lo((v)[u].z); d5 = bf_hi((v)[u].z);              \
            d6 = bf_lo((v)[u].w); d7 = bf_hi((v)[u].w);              \
        } else {                                                     \
            float2 fa = h2f((v)[u].x), fb = h2f((v)[u].y);           \
            float2 fc = h2f((v)[u].z), fd = h2f((v)[u].w);           \
            d0 = fa.x; d1 = fa.y; d2 = fb.x; d3 = fb.y;              \
            d4 = fc.x; d5 = fc.y; d6 = fd.x; d7 = fd.y;              \
        }                                                            \
        f[0] = fmaf(w, d0, f[0]); f[1] = fmaf(w, d1, f[1]);          \
        f[2] = fmaf(w, d2, f[2]); f[3] = fmaf(w, d3, f[3]);          \
        f[4] = fmaf(w, d4, f[4]); f[5] = fmaf(w, d5, f[5]);          \
        f[6] = fmaf(w, d6, f[6]); f[7] = fmaf(w, d7, f[7]);          \
    }

    if (nfull > 0) {
        LD_CSR(cwA, s);
        if (nfull > 1) LD_CSR(cwB, s + 16);
        GATHER(vA, cwA);
        int c = 0;
        while (true) {
            // chunk c in A, chunk c+1 in B
            if (c + 1 < nfull) GATHER(vB, cwB);
            FMA2(cwA, vA);
            if (c + 1 >= nfull) break;
            if (c + 2 < nfull) LD_CSR(cwA, s + (c + 2) * 16);
            ++c;
            // chunk c in B, chunk c+1 in A
            if (c + 1 < nfull) GATHER(vA, cwA);
            FMA2(cwB, vB);
            if (c + 1 >= nfull) break;
            if (c + 2 < nfull) LD_CSR(cwB, s + (c + 2) * 16);
            ++c;
        }
    }
    if (rem) {
        const int base = s + nfull * 16;
        int2 cw[2];
        #pragma unroll
        for (int u = 0; u < 2; ++u) {
            int idx = base + 8 * u + q;
            int j = (idx < e) ? idx : (e - 1);
            cw[u] = csr[j];
            if (idx >= e) cw[u].y = 0;     // w = 0 for padding slots
        }
        uint4 v[2];
        #pragma unroll
        for (int u = 0; u < 2; ++u)
            v[u] = p[(size_t)((unsigned int)cw[u].x * 8u + hl)];
        FMA2(cw, v);
    }
#undef LD_CSR
#undef GATHER
#undef FMA2
}

// LAST fuses epilogue: out = (emb0 + h1 + h2 + h3)/4.
template <bool LAST>
__global__ void hop_kernel(const int* __restrict__ rowptr,
                           const int2* __restrict__ csr,
                           const void* __restrict__ prev,
                           void* __restrict__ next,
                           const void* __restrict__ E0,   // emb0 (LAST only)
                           const void* __restrict__ H1,   // h1   (LAST only)
                           void* __restrict__ out,
                           const int* __restrict__ flag)
{
    int row = blockIdx.x * (blockDim.x >> 6) + (threadIdx.x >> 6);
    if (row >= N_NODES) return;
    const int q  = (threadIdx.x >> 3) & 7;
    const int hl = threadIdx.x & 7;
    const bool isb = ((*flag) & 1);
    const int s = rowptr[row], e = rowptr[row + 1];
    const uint4* p = (const uint4*)prev;
    float f[8] = {0.f, 0.f, 0.f, 0.f, 0.f, 0.f, 0.f, 0.f};
    if (isb) gather_row8<true >(csr, p, s, e, q, hl, f);
    else     gather_row8<false>(csr, p, s, e, q, hl, f);
    #pragma unroll
    for (int k = 0; k < 8; ++k) {        // combine the 8 edge-slot groups
        f[k] += __shfl_xor(f[k], 8);
        f[k] += __shfl_xor(f[k], 16);
        f[k] += __shfl_xor(f[k], 32);
    }
    if ((threadIdx.x & 56) != 0) return; // slot-0 lanes (8 per row) write
    size_t o16 = (size_t)row * 8 + hl;   // 8-element (16-byte) units
    if (LAST) {
        uint4 e0u = ((const uint4*)E0)[o16];
        uint4 h1u = ((const uint4*)H1)[o16];
        uint4 h2u = ((const uint4*)prev)[o16];
        float v[8];
        if (isb) {
            v[0] = (bf_lo(e0u.x) + bf_lo(h1u.x) + bf_lo(h2u.x) + f[0]) * 0.25f;
            v[1] = (bf_hi(e0u.x) + bf_hi(h1u.x) + bf_hi(h2u.x) + f[1]) * 0.25f;
            v[2] = (bf_lo(e0u.y) + bf_lo(h1u.y) + bf_lo(h2u.y) + f[2]) * 0.25f;
            v[3] = (bf_hi(e0u.y) + bf_hi(h1u.y) + bf_hi(h2u.y) + f[3]) * 0.25f;
            v[4] = (bf_lo(e0u.z) + bf_lo(h1u.z) + bf_lo(h2u.z) + f[4]) * 0.25f;
            v[5] = (bf_hi(e0u.z) + bf_hi(h1u.z) + bf_hi(h2u.z) + f[5]) * 0.25f;
            v[6] = (bf_lo(e0u.w) + bf_lo(h1u.w) + bf_lo(h2u.w) + f[6]) * 0.25f;
            v[7] = (bf_hi(e0u.w) + bf_hi(h1u.w) + bf_hi(h2u.w) + f[7]) * 0.25f;
            uint4 o;
            o.x = pack_bf16(v[0], v[1]);
            o.y = pack_bf16(v[2], v[3]);
            o.z = pack_bf16(v[4], v[5]);
            o.w = pack_bf16(v[6], v[7]);
            size_t oo = o16 + ((row < NUM_USERS) ? 0 : (size_t)(U_ELEMS / 8));
            ((uint4*)out)[oo] = o;
        } else {
            float2 a0 = h2f(e0u.x), a1 = h2f(e0u.y), a2 = h2f(e0u.z), a3 = h2f(e0u.w);
            float2 b0 = h2f(h1u.x), b1 = h2f(h1u.y), b2 = h2f(h1u.z), b3 = h2f(h1u.w);
            float2 c0 = h2f(h2u.x), c1 = h2f(h2u.y), c2 = h2f(h2u.z), c3 = h2f(h2u.w);
            v[0] = (a0.x + b0.x + c0.x + f[0]) * 0.25f;
            v[1] = (a0.y + b0.y + c0.y + f[1]) * 0.25f;
            v[2] = (a1.x + b1.x + c1.x + f[2]) * 0.25f;
            v[3] = (a1.y + b1.y + c1.y + f[3]) * 0.25f;
            v[4] = (a2.x + b2.x + c2.x + f[4]) * 0.25f;
            v[5] = (a2.y + b2.y + c2.y + f[5]) * 0.25f;
            v[6] = (a3.x + b3.x + c3.x + f[6]) * 0.25f;
            v[7] = (a3.y + b3.y + c3.y + f[7]) * 0.25f;
            size_t fo = (size_t)row * 64 + (size_t)hl * 8 +
                        ((row < NUM_USERS) ? 0 : (size_t)U_ELEMS);
            float4* op = (float4*)((float*)out + fo);
            op[0] = make_float4(v[0], v[1], v[2], v[3]);
            op[1] = make_float4(v[4], v[5], v[6], v[7]);
        }
    } else {
        uint4 o;
        if (isb) {
            o.x = pack_bf16(f[0], f[1]);
            o.y = pack_bf16(f[2], f[3]);
            o.z = pack_bf16(f[4], f[5]);
            o.w = pack_bf16(f[6], f[7]);
        } else {
            __half2 ha = __floats2half2_rn(f[0], f[1]);
            __half2 hb = __floats2half2_rn(f[2], f[3]);
            __half2 hc = __floats2half2_rn(f[4], f[5]);
            __half2 hd = __floats2half2_rn(f[6], f[7]);
            o.x = *reinterpret_cast<unsigned int*>(&ha);
            o.y = *reinterpret_cast<unsigned int*>(&hb);
            o.z = *reinterpret_cast<unsigned int*>(&hc);
            o.w = *reinterpret_cast<unsigned int*>(&hd);
        }
        ((uint4*)next)[o16] = o;
    }
}

// ---------- R3 atomic fallback ----------

__global__ void init_kernel(const void* __restrict__ users,
                            const void* __restrict__ items,
                            void* __restrict__ out,
                            float* __restrict__ A,
                            float* __restrict__ B,
                            float* __restrict__ ACC,
                            const int* __restrict__ flag)
{
    int gid = blockIdx.x * blockDim.x + threadIdx.x;
    if (gid >= NODE_ELEMS) return;
    const bool isb = ((*flag) & 1);
    float v;
    if (gid < U_ELEMS) {
        if (isb) { bf16 b = ((const bf16*)users)[gid]; v = __bfloat162float(b); ((bf16*)out)[U_ELEMS + gid] = b; }
        else     { float fv = ((const float*)users)[gid]; v = fv; ((float*)out)[U_ELEMS + gid] = fv; }
    } else {
        int ii = gid - U_ELEMS;
        if (isb) { bf16 b = ((const bf16*)items)[ii]; v = __bfloat162float(b); ((bf16*)out)[2 * U_ELEMS + I_ELEMS + ii] = b; }
        else     { float fv = ((const float*)items)[ii]; v = fv; ((float*)out)[2 * U_ELEMS + I_ELEMS + ii] = fv; }
    }
    A[gid]   = v;
    B[gid]   = 0.0f;
    ACC[gid] = v;
}

__global__ void finalize_kernel(const float* __restrict__ acc,
                                void* __restrict__ out,
                                const int* __restrict__ flag)
{
    int gid = blockIdx.x * blockDim.x + threadIdx.x;
    if (gid >= NODE_ELEMS) return;
    const bool isb = ((*flag) & 1);
    float v = acc[gid] * 0.25f;
    size_t o = (gid < U_ELEMS) ? (size_t)gid : (size_t)(2 * U_ELEMS + (gid - U_ELEMS));
    if (isb) ((bf16*)out)[o]  = __float2bfloat16(v);
    else     ((float*)out)[o] = v;
}

__global__ void scatter_kernel(const int* __restrict__ ei32,
                               const void* __restrict__ ew,
                               const float* __restrict__ prev,
                               float* __restrict__ next,
                               const int* __restrict__ flag)
{
    int gid = blockIdx.x * blockDim.x + threadIdx.x;
    if (gid >= N_EDGES * 16) return;
    const int f = *flag;
    int e = gid >> 4;
    int j = (gid & 15) << 2;
    int row = load_row(ei32, f, e);
    int col = load_col(ei32, f, e);
    float w = load_w(ew, f, e);
    const float4 v = *reinterpret_cast<const float4*>(prev + (size_t)col * EMB + j);
    float* dst = next + (size_t)row * EMB + j;
    unsafeAtomicAdd(dst + 0, w * v.x);
    unsafeAtomicAdd(dst + 1, w * v.y);
    unsafeAtomicAdd(dst + 2, w * v.z);
    unsafeAtomicAdd(dst + 3, w * v.w);
}

__global__ void accum_zero_kernel(float* __restrict__ acc,
                                  const float* __restrict__ next,
                                  float* __restrict__ prevz)
{
    int gid = blockIdx.x * blockDim.x + threadIdx.x;
    if (gid >= NODE_ELEMS) return;
    acc[gid] += next[gid];
    prevz[gid] = 0.0f;
}

__global__ void sentinel_kernel(unsigned int* __restrict__ out, int nwords)
{
    int gid = blockIdx.x * blockDim.x + threadIdx.x;
    if (gid < nwords) out[gid] = 0x447A447Au;
}

extern "C" void kernel_launch(void* const* d_in, const int* in_sizes, int n_in,
                              void* d_out, int out_size, void* d_ws, size_t ws_size,
                              hipStream_t stream)
{
    const void* users = d_in[0];
    const void* items = d_in[1];
    const int*  ei32  = (const int*)d_in[2];
    const void* ew    = d_in[3];

    char* wsb  = (char*)d_ws;
    int*  flag = (int*)wsb;
    float* A   = (float*)(wsb + 256);              // fp32-sized; holds 16-bit in CSR path
    float* B   = A + (size_t)NODE_ELEMS;           // h1 buffer; aliases rec
    float* ACC = B + (size_t)NODE_ELEMS;           // h2 buffer in CSR path
    char* p    = (char*)(ACC + (size_t)NODE_ELEMS);
    int*  rowptr      = (int*)p;  p += (N_NODES + 4) * sizeof(int);
    int*  bucket_cnt  = (int*)p;  p += (NB + 2) * sizeof(int);
    int*  bucket_base = (int*)p;  p += (NB + 2) * sizeof(int);
    int*  bucket_off  = (int*)p;  p += (NB + 2) * sizeof(int);
    int2* csr         = (int2*)p; p += (size_t)N_EDGES * sizeof(int2);  // packed (col,w)
    int2* rec         = (int2*)B;                  // alias: dead before hop1 writes B

    const size_t need_csr    = (size_t)(p - wsb);                  // ~154.4 MB
    const size_t need_atomic = 256 + 3 * (size_t)NODE_ELEMS * sizeof(float);
    const int BLK = 256;
    const int node_blocks = (NODE_ELEMS + BLK - 1) / BLK;
    const int vec_blocks  = (NODE_ELEMS / 4 + BLK - 1) / BLK;
    const int row_blocks  = (N_NODES + 3) / 4;       // 4 rows (waves) per block
    const int bin_blocks  = (N_EDGES + EPB - 1) / EPB;   // 1172

    if (ws_size >= need_csr) {
        float* C = ACC;   // h2 buffer
        detect_kernel<<<1, BLK, 0, stream>>>((const unsigned short*)users, ei32, flag, bucket_cnt);
        init_vec_kernel<<<vec_blocks, BLK, 0, stream>>>(users, items, d_out, A, flag);
        bucket_hist_kernel<<<1024, BLK, 0, stream>>>(ei32, bucket_cnt, flag);
        bucket_scan_kernel<<<1, 1024, 0, stream>>>(bucket_cnt, bucket_base, bucket_off);
        bin_kernel<<<bin_blocks, 1024, 0, stream>>>(ei32, ew, bucket_off, rec, flag);
        local_fill_kernel<<<NB, RPB, 0, stream>>>(bucket_base, rec, csr, rowptr);

        // hop1: A(emb0) -> B(h1); hop2: B -> C(h2); hop3: C -> out, fusing
        // out = (A + B + C + h3)/4 in the epilogue.
        hop_kernel<false><<<row_blocks, BLK, 0, stream>>>(rowptr, csr, A, B, nullptr, nullptr, nullptr, flag);
        hop_kernel<false><<<row_blocks, BLK, 0, stream>>>(rowptr, csr, B, C, nullptr, nullptr, nullptr, flag);
        hop_kernel<true ><<<row_blocks, BLK, 0, stream>>>(rowptr, csr, C, nullptr, A, B, d_out, flag);
    } else if (ws_size >= need_atomic) {
        const int sedge_blocks = (N_EDGES * 16 + BLK - 1) / BLK;
        detect_kernel<<<1, BLK, 0, stream>>>((const unsigned short*)users, ei32, flag, bucket_cnt);
        init_kernel<<<node_blocks, BLK, 0, stream>>>(users, items, d_out, A, B, ACC, flag);
        float* prev = A;
        float* nxt  = B;
        for (int h = 0; h < 3; ++h) {
            scatter_kernel<<<sedge_blocks, BLK, 0, stream>>>(ei32, ew, prev, nxt, flag);
            accum_zero_kernel<<<node_blocks, BLK, 0, stream>>>(ACC, nxt, prev);
            float* t = prev; prev = nxt; nxt = t;
        }
        finalize_kernel<<<node_blocks, BLK, 0, stream>>>(ACC, d_out, flag);
    } else {
        int nwords = out_size / 2;
        sentinel_kernel<<<(nwords + BLK - 1) / BLK, BLK, 0, stream>>>((unsigned int*)d_out, nwords);
    }
}

// Round 11
// 502.205 us; speedup vs baseline: 2.8363x; 1.0692x over previous
//
#include <hip/hip_runtime.h>
#include <hip/hip_bf16.h>
#include <hip/hip_fp16.h>

// LightGCN 3-hop propagation, 150k nodes, 4.8M edges, EMB=64.
// Round 16 (session R10):
//  - build: bucket_hist + pre-scan ELIMINATED. Buckets get fixed-capacity
//    rec regions (CAP=9216 = mean 8192 + 11 sigma; clamped writes). bin
//    appends into bucket_off[b] (init b*CAP in detect); the tiny 586-entry
//    scan runs AFTER bin (counts = off - b*CAP) so csr stays dense and
//    rowptr/hop are untouched. Saves one full 4.8M-edge pass + a launch.
//  - bin: int64 row/col loads vectorized as int2 (stride-2 4B reads wasted
//    half of each line: 153.6 -> 76.8MB effective).
// R15 kept: uint4 hop gathers (8 edges/instr; 139.6->115.2->94.1us ladder).
// R14 kept: per-row hop launch. R11: depth-2 pipeline + predicated tail.
// R9: fp16 internal storage, packed int2 csr, fused epilogue.

#define NUM_USERS 100000
#define NUM_ITEMS 50000
#define N_NODES   150000
#define EMB       64
#define N_EDGES   4800000
#define NODE_ELEMS (N_NODES * EMB)   // 9,600,000
#define U_ELEMS    (NUM_USERS * EMB) // 6,400,000
#define I_ELEMS    (NUM_ITEMS * EMB) // 3,200,000

#define RPB 256                       // rows per bucket (2^8: row>>8, row&255)
#define NB  ((N_NODES + RPB - 1) / RPB)   // 586 buckets
#define CAP 9216                      // bucket capacity (mean 8192, sigma~90)
#define EPB 4096                      // edges staged per bin block
#define EPW (EPB / 1024)              // edges per thread in bin_kernel

typedef __hip_bfloat16 bf16;

__device__ __forceinline__ unsigned int pack_bf16(float a, float b) {
    bf16 x = __float2bfloat16(a), y = __float2bfloat16(b);
    return ((unsigned int)(*reinterpret_cast<unsigned short*>(&y)) << 16) |
           (*reinterpret_cast<unsigned short*>(&x));
}
__device__ __forceinline__ float bf_lo(unsigned int u) { return __uint_as_float(u << 16); }
__device__ __forceinline__ float bf_hi(unsigned int u) { return __uint_as_float(u & 0xffff0000u); }
__device__ __forceinline__ float2 h2f(unsigned int u) {
    return __half22float2(*reinterpret_cast<const __half2*>(&u));
}

// flag bit0: float arrays are bf16 (else fp32). bit1: edge_index int64 (else int32).
__global__ void detect_kernel(const unsigned short* __restrict__ u16,
                              const int* __restrict__ ei32,
                              int* __restrict__ flag,
                              int* __restrict__ bucket_off)
{
    __shared__ int s_fp32, s_i32;
    if (threadIdx.x == 0) { s_fp32 = 0; s_i32 = 0; }
    __syncthreads();
    int t = threadIdx.x;
    for (int i = t; i < NB + 1; i += 256) bucket_off[i] = i * CAP;
    unsigned short u = u16[t];
    int e = (u >> 7) & 0xFF;
    if (e >= 0xC0) atomicOr(&s_fp32, 1);
    if (t < 64 && ei32[2 * t + 1] != 0) atomicOr(&s_i32, 1);
    __syncthreads();
    if (t == 0) {
        int f = 0;
        if (!s_fp32) f |= 1;
        if (!s_i32)  f |= 2;
        *flag = f;
    }
}

__device__ __forceinline__ int load_row(const int* ei32, int f, size_t e) {
    return (f & 2) ? ei32[2 * e] : ei32[e];
}
__device__ __forceinline__ int load_col(const int* ei32, int f, size_t e) {
    return (f & 2) ? ei32[2 * ((size_t)N_EDGES + e)] : ei32[(size_t)N_EDGES + e];
}
__device__ __forceinline__ float load_w(const void* ew, int f, size_t e) {
    return (f & 1) ? __bfloat162float(((const bf16*)ew)[e]) : ((const float*)ew)[e];
}

// ---------- vectorized init: A (16-bit packed) + passthrough ----------
__global__ void init_vec_kernel(const void* __restrict__ users,
                                const void* __restrict__ items,
                                void* __restrict__ out,
                                void* __restrict__ A,
                                const int* __restrict__ flag)
{
    int g = blockIdx.x * blockDim.x + threadIdx.x;   // NODE_ELEMS/4 threads
    if (g >= NODE_ELEMS / 4) return;
    int g4 = g * 4;
    const bool isb = ((*flag) & 1);
    if (isb) {
        uint2 v;
        if (g4 < U_ELEMS) {
            v = ((const uint2*)users)[g];
            ((uint2*)((bf16*)out + U_ELEMS))[g] = v;
        } else {
            int ii = g - U_ELEMS / 4;
            v = ((const uint2*)items)[ii];
            ((uint2*)((bf16*)out + 2 * (size_t)U_ELEMS + I_ELEMS))[ii] = v;
        }
        ((uint2*)A)[g] = v;            // A stored bf16
    } else {
        float4 v;
        if (g4 < U_ELEMS) {
            v = ((const float4*)users)[g];
            ((float4*)((float*)out + U_ELEMS))[g] = v;
        } else {
            int ii = g - U_ELEMS / 4;
            v = ((const float4*)items)[ii];
            ((float4*)((float*)out + 2 * (size_t)U_ELEMS + I_ELEMS))[ii] = v;
        }
        __half2 ha = __floats2half2_rn(v.x, v.y);
        __half2 hb = __floats2half2_rn(v.z, v.w);
        uint2 u2;
        u2.x = *reinterpret_cast<unsigned int*>(&ha);
        u2.y = *reinterpret_cast<unsigned int*>(&hb);
        ((uint2*)A)[g] = u2;           // A stored fp16 (intermediates 16-bit)
    }
}

// ---------- binned CSR build (fixed-capacity buckets) ----------

// stage EPB edges in LDS, rank by bucket, append bucket-contiguous runs
// into fixed-capacity rec regions [b*CAP, (b+1)*CAP).
__global__ __launch_bounds__(1024) void bin_kernel(const int* __restrict__ ei32,
                                                   const void* __restrict__ ew,
                                                   int* __restrict__ bucket_off,
                                                   int2* __restrict__ rec,
                                                   const int* __restrict__ flag)
{
    __shared__ int2 stage[EPB];            // 32 KB
    __shared__ unsigned short bof[EPB];    // 8 KB
    __shared__ int hist[NB], excl0[NB], rank_[NB], gbase[NB];
    __shared__ int ls[16];
    const int t = threadIdx.x;
    const size_t base_e = (size_t)blockIdx.x * EPB;
    const int cnt = (int)(((base_e + EPB) <= N_EDGES) ? EPB : (N_EDGES - base_e));
    for (int i = t; i < NB; i += 1024) hist[i] = 0;
    __syncthreads();
    const int f = *flag;
    int  mybkt[EPW];
    int2 myrec[EPW];
    #pragma unroll
    for (int k = 0; k < EPW; ++k) {
        int idx = k * 1024 + t;
        if (idx < cnt) {
            size_t e = base_e + idx;
            int row, col;
            if (f & 2) {   // int64 input: int2 vector load, keep low word
                row = ((const int2*)ei32)[e].x;
                col = ((const int2*)ei32)[(size_t)N_EDGES + e].x;
            } else {
                row = ei32[e];
                col = ei32[(size_t)N_EDGES + e];
            }
            float w = load_w(ew, f, e);
            mybkt[k] = row >> 8;
            myrec[k] = make_int2(col | ((row & 255) << 18), __float_as_int(w));
            atomicAdd(&hist[mybkt[k]], 1);
        } else mybkt[k] = -1;
    }
    __syncthreads();
    {   // scan hist[0..NB) -> excl0, rank_
        const int lane = t & 63, wv = t >> 6;
        int x = (t < NB) ? hist[t] : 0;
        int v = x;
        #pragma unroll
        for (int d = 1; d < 64; d <<= 1) { int y = __shfl_up(v, d, 64); if (lane >= d) v += y; }
        if (lane == 63) ls[wv] = v;
        __syncthreads();
        if (wv == 0 && lane < 16) {
            int s = ls[lane];
            #pragma unroll
            for (int d = 1; d < 16; d <<= 1) { int y = __shfl_up(s, d, 64); if (lane >= d) s += y; }
            ls[lane] = s;
        }
        __syncthreads();
        int waveoff = wv ? ls[wv - 1] : 0;
        int excl = waveoff + v - x;
        if (t < NB) { excl0[t] = excl; rank_[t] = excl; }
    }
    __syncthreads();
    if (t < NB && hist[t] > 0) gbase[t] = atomicAdd(&bucket_off[t], hist[t]);
    else if (t < NB)           gbase[t] = 0;
    #pragma unroll
    for (int k = 0; k < EPW; ++k) {
        if (mybkt[k] >= 0) {
            int p = atomicAdd(&rank_[mybkt[k]], 1);
            stage[p] = myrec[k];
            bof[p]   = (unsigned short)mybkt[k];
        }
    }
    __syncthreads();
    for (int s = t; s < cnt; s += 1024) {
        int b = bof[s];
        int pos = gbase[b] + (s - excl0[b]);
        if (pos < (b + 1) * CAP)           // overflow clamp (11-sigma margin)
            rec[pos] = stage[s];
    }
}

// post-bin scan: counts = bucket_off[b] - b*CAP -> dense exclusive prefix.
__global__ void bucket_scan_kernel(const int* __restrict__ bucket_off,
                                   int* __restrict__ bucket_base,
                                   int* __restrict__ bucket_cnt)
{
    __shared__ int ls[16];
    const int t = threadIdx.x;           // 1024 threads, NB <= 1024
    const int lane = t & 63, wv = t >> 6;
    int x = 0;
    if (t < NB) {
        x = bucket_off[t] - t * CAP;
        if (x > CAP) x = CAP;
    }
    int v = x;
    #pragma unroll
    for (int d = 1; d < 64; d <<= 1) { int y = __shfl_up(v, d, 64); if (lane >= d) v += y; }
    if (lane == 63) ls[wv] = v;
    __syncthreads();
    if (wv == 0 && lane < 16) {
        int s = ls[lane];
        #pragma unroll
        for (int d = 1; d < 16; d <<= 1) { int y = __shfl_up(s, d, 64); if (lane >= d) s += y; }
        ls[lane] = s;
    }
    __syncthreads();
    int waveoff = wv ? ls[wv - 1] : 0;
    int excl = waveoff + v - x;
    if (t < NB) { bucket_base[t] = excl; bucket_cnt[t] = x; }
    if (t == 0) bucket_base[NB] = ls[15];   // total (== N_EDGES normally)
}

// one block per bucket: local row hist + scan -> rowptr; scatter packed
// (col,w) csr (dense) from the bucket's fixed-cap rec region.
__global__ void local_fill_kernel(const int* __restrict__ bucket_base,
                                  const int* __restrict__ bucket_cnt,
                                  const int2* __restrict__ rec,
                                  int2* __restrict__ csr,
                                  int* __restrict__ rowptr)
{
    __shared__ int hist[RPB], off[RPB], ls[4];
    const int b = blockIdx.x, t = threadIdx.x;      // 256 threads
    const int src = b * CAP;
    const int cnt = bucket_cnt[b];
    const int dlo = bucket_base[b];
    const int rows = (N_NODES - b * RPB < RPB) ? (N_NODES - b * RPB) : RPB;
    hist[t] = 0;
    __syncthreads();
    for (int s = t; s < cnt; s += 256)
        atomicAdd(&hist[rec[src + s].x >> 18], 1);
    __syncthreads();
    const int lane = t & 63, wv = t >> 6;
    int x = hist[t];
    int v = x;
    #pragma unroll
    for (int d = 1; d < 64; d <<= 1) { int y = __shfl_up(v, d, 64); if (lane >= d) v += y; }
    if (lane == 63) ls[wv] = v;
    __syncthreads();
    if (wv == 0 && lane < 4) {
        int s = ls[lane];
        #pragma unroll
        for (int d = 1; d < 4; d <<= 1) { int y = __shfl_up(s, d, 64); if (lane >= d) s += y; }
        ls[lane] = s;
    }
    __syncthreads();
    int waveoff = wv ? ls[wv - 1] : 0;
    int excl = waveoff + v - x;
    if (t < rows) rowptr[b * RPB + t] = dlo + excl;
    off[t] = dlo + excl;
    if (b == NB - 1 && t == 0) rowptr[N_NODES] = bucket_base[NB];
    __syncthreads();
    for (int s = t; s < cnt; s += 256) {
        int2 r = rec[src + s];
        int rl = r.x >> 18;
        int pos = atomicAdd(&off[rl], 1);
        csr[pos] = make_int2(r.x & 0x3FFFF, r.y);   // packed (col, w-bits)
    }
}

// ---------- gather hop core: uint4 gathers ----------
// Lane q=(tid>>3)&7 owns edge-slot q of each 8-edge step; hl=tid&7 owns
// dims {8hl..8hl+7} as one uint4 (8 x 16-bit). 16-edge chunk = 2 steps.
// Main loop: depth-2 pipeline. Tail: ONE predicated 16-slot step.

template <bool ISB>
__device__ __forceinline__ void gather_row8(const int2* __restrict__ csr,
                                            const uint4* __restrict__ p,
                                            int s, int e, int q, int hl,
                                            float f[8])
{
    const int len   = e - s;
    const int nfull = len >> 4;          // full 16-edge chunks
    const int rem   = len & 15;

    int2 cwA[2], cwB[2];
    uint4 vA[2], vB[2];

#define LD_CSR(cw, base)                                             \
    _Pragma("unroll")                                                \
    for (int u = 0; u < 2; ++u) (cw)[u] = csr[(base) + 8 * u + q];
#define GATHER(v, cw)                                                \
    _Pragma("unroll")                                                \
    for (int u = 0; u < 2; ++u)                                      \
        (v)[u] = p[(size_t)((unsigned int)(cw)[u].x * 8u + hl)];
#define FMA2(cw, v)                                                  \
    _Pragma("unroll")                                                \
    for (int u = 0; u < 2; ++u) {                                    \
        float w = __int_as_float((cw)[u].y);                         \
        float d0, d1, d2, d3, d4, d5, d6, d7;                        \
        if (ISB) {                                                   \
            d0 = bf_lo((v)[u].x); d1 = bf_hi((v)[u].x);              \
            d2 = bf_lo((v)[u].y); d3 = bf_hi((v)[u].y);              \
            d4 = bf_lo((v)[u].z); d5 = bf_hi((v)[u].z);              \
            d6 = bf_lo((v)[u].w); d7 = bf_hi((v)[u].w);              \
        } else {                                                     \
            float2 fa = h2f((v)[u].x), fb = h2f((v)[u].y);           \
            float2 fc = h2f((v)[u].z), fd = h2f((v)[u].w);           \
            d0 = fa.x; d1 = fa.y; d2 = fb.x; d3 = fb.y;              \
            d4 = fc.x; d5 = fc.y; d6 = fd.x; d7 = fd.y;              \
        }                                                            \
        f[0] = fmaf(w, d0, f[0]); f[1] = fmaf(w, d1, f[1]);          \
        f[2] = fmaf(w, d2, f[2]); f[3] = fmaf(w, d3, f[3]);          \
        f[4] = fmaf(w, d4, f[4]); f[5] = fmaf(w, d5, f[5]);          \
        f[6] = fmaf(w, d6, f[6]); f[7] = fmaf(w, d7, f[7]);          \
    }

    if (nfull > 0) {
        LD_CSR(cwA, s);
        if (nfull > 1) LD_CSR(cwB, s + 16);
        GATHER(vA, cwA);
        int c = 0;
        while (true) {
            // chunk c in A, chunk c+1 in B
            if (c + 1 < nfull) GATHER(vB, cwB);
            FMA2(cwA, vA);
            if (c + 1 >= nfull) break;
            if (c + 2 < nfull) LD_CSR(cwA, s + (c + 2) * 16);
            ++c;
            // chunk c in B, chunk c+1 in A
            if (c + 1 < nfull) GATHER(vA, cwA);
            FMA2(cwB, vB);
            if (c + 1 >= nfull) break;
            if (c + 2 < nfull) LD_CSR(cwB, s + (c + 2) * 16);
            ++c;
        }
    }
    if (rem) {
        const int base = s + nfull * 16;
        int2 cw[2];
        #pragma unroll
        for (int u = 0; u < 2; ++u) {
            int idx = base + 8 * u + q;
            int j = (idx < e) ? idx : (e - 1);
            cw[u] = csr[j];
            if (idx >= e) cw[u].y = 0;     // w = 0 for padding slots
        }
        uint4 v[2];
        #pragma unroll
        for (int u = 0; u < 2; ++u)
            v[u] = p[(size_t)((unsigned int)cw[u].x * 8u + hl)];
        FMA2(cw, v);
    }
#undef LD_CSR
#undef GATHER
#undef FMA2
}

// LAST fuses epilogue: out = (emb0 + h1 + h2 + h3)/4.
template <bool LAST>
__global__ void hop_kernel(const int* __restrict__ rowptr,
                           const int2* __restrict__ csr,
                           const void* __restrict__ prev,
                           void* __restrict__ next,
                           const void* __restrict__ E0,   // emb0 (LAST only)
                           const void* __restrict__ H1,   // h1   (LAST only)
                           void* __restrict__ out,
                           const int* __restrict__ flag)
{
    int row = blockIdx.x * (blockDim.x >> 6) + (threadIdx.x >> 6);
    if (row >= N_NODES) return;
    const int q  = (threadIdx.x >> 3) & 7;
    const int hl = threadIdx.x & 7;
    const bool isb = ((*flag) & 1);
    const int s = rowptr[row], e = rowptr[row + 1];
    const uint4* p = (const uint4*)prev;
    float f[8] = {0.f, 0.f, 0.f, 0.f, 0.f, 0.f, 0.f, 0.f};
    if (isb) gather_row8<true >(csr, p, s, e, q, hl, f);
    else     gather_row8<false>(csr, p, s, e, q, hl, f);
    #pragma unroll
    for (int k = 0; k < 8; ++k) {        // combine the 8 edge-slot groups
        f[k] += __shfl_xor(f[k], 8);
        f[k] += __shfl_xor(f[k], 16);
        f[k] += __shfl_xor(f[k], 32);
    }
    if ((threadIdx.x & 56) != 0) return; // slot-0 lanes (8 per row) write
    size_t o16 = (size_t)row * 8 + hl;   // 8-element (16-byte) units
    if (LAST) {
        uint4 e0u = ((const uint4*)E0)[o16];
        uint4 h1u = ((const uint4*)H1)[o16];
        uint4 h2u = ((const uint4*)prev)[o16];
        float v[8];
        if (isb) {
            v[0] = (bf_lo(e0u.x) + bf_lo(h1u.x) + bf_lo(h2u.x) + f[0]) * 0.25f;
            v[1] = (bf_hi(e0u.x) + bf_hi(h1u.x) + bf_hi(h2u.x) + f[1]) * 0.25f;
            v[2] = (bf_lo(e0u.y) + bf_lo(h1u.y) + bf_lo(h2u.y) + f[2]) * 0.25f;
            v[3] = (bf_hi(e0u.y) + bf_hi(h1u.y) + bf_hi(h2u.y) + f[3]) * 0.25f;
            v[4] = (bf_lo(e0u.z) + bf_lo(h1u.z) + bf_lo(h2u.z) + f[4]) * 0.25f;
            v[5] = (bf_hi(e0u.z) + bf_hi(h1u.z) + bf_hi(h2u.z) + f[5]) * 0.25f;
            v[6] = (bf_lo(e0u.w) + bf_lo(h1u.w) + bf_lo(h2u.w) + f[6]) * 0.25f;
            v[7] = (bf_hi(e0u.w) + bf_hi(h1u.w) + bf_hi(h2u.w) + f[7]) * 0.25f;
            uint4 o;
            o.x = pack_bf16(v[0], v[1]);
            o.y = pack_bf16(v[2], v[3]);
            o.z = pack_bf16(v[4], v[5]);
            o.w = pack_bf16(v[6], v[7]);
            size_t oo = o16 + ((row < NUM_USERS) ? 0 : (size_t)(U_ELEMS / 8));
            ((uint4*)out)[oo] = o;
        } else {
            float2 a0 = h2f(e0u.x), a1 = h2f(e0u.y), a2 = h2f(e0u.z), a3 = h2f(e0u.w);
            float2 b0 = h2f(h1u.x), b1 = h2f(h1u.y), b2 = h2f(h1u.z), b3 = h2f(h1u.w);
            float2 c0 = h2f(h2u.x), c1 = h2f(h2u.y), c2 = h2f(h2u.z), c3 = h2f(h2u.w);
            v[0] = (a0.x + b0.x + c0.x + f[0]) * 0.25f;
            v[1] = (a0.y + b0.y + c0.y + f[1]) * 0.25f;
            v[2] = (a1.x + b1.x + c1.x + f[2]) * 0.25f;
            v[3] = (a1.y + b1.y + c1.y + f[3]) * 0.25f;
            v[4] = (a2.x + b2.x + c2.x + f[4]) * 0.25f;
            v[5] = (a2.y + b2.y + c2.y + f[5]) * 0.25f;
            v[6] = (a3.x + b3.x + c3.x + f[6]) * 0.25f;
            v[7] = (a3.y + b3.y + c3.y + f[7]) * 0.25f;
            size_t fo = (size_t)row * 64 + (size_t)hl * 8 +
                        ((row < NUM_USERS) ? 0 : (size_t)U_ELEMS);
            float4* op = (float4*)((float*)out + fo);
            op[0] = make_float4(v[0], v[1], v[2], v[3]);
            op[1] = make_float4(v[4], v[5], v[6], v[7]);
        }
    } else {
        uint4 o;
        if (isb) {
            o.x = pack_bf16(f[0], f[1]);
            o.y = pack_bf16(f[2], f[3]);
            o.z = pack_bf16(f[4], f[5]);
            o.w = pack_bf16(f[6], f[7]);
        } else {
            __half2 ha = __floats2half2_rn(f[0], f[1]);
            __half2 hb = __floats2half2_rn(f[2], f[3]);
            __half2 hc = __floats2half2_rn(f[4], f[5]);
            __half2 hd = __floats2half2_rn(f[6], f[7]);
            o.x = *reinterpret_cast<unsigned int*>(&ha);
            o.y = *reinterpret_cast<unsigned int*>(&hb);
            o.z = *reinterpret_cast<unsigned int*>(&hc);
            o.w = *reinterpret_cast<unsigned int*>(&hd);
        }
        ((uint4*)next)[o16] = o;
    }
}

// ---------- R3 atomic fallback ----------

__global__ void init_kernel(const void* __restrict__ users,
                            const void* __restrict__ items,
                            void* __restrict__ out,
                            float* __restrict__ A,
                            float* __restrict__ B,
                            float* __restrict__ ACC,
                            const int* __restrict__ flag)
{
    int gid = blockIdx.x * blockDim.x + threadIdx.x;
    if (gid >= NODE_ELEMS) return;
    const bool isb = ((*flag) & 1);
    float v;
    if (gid < U_ELEMS) {
        if (isb) { bf16 b = ((const bf16*)users)[gid]; v = __bfloat162float(b); ((bf16*)out)[U_ELEMS + gid] = b; }
        else     { float fv = ((const float*)users)[gid]; v = fv; ((float*)out)[U_ELEMS + gid] = fv; }
    } else {
        int ii = gid - U_ELEMS;
        if (isb) { bf16 b = ((const bf16*)items)[ii]; v = __bfloat162float(b); ((bf16*)out)[2 * U_ELEMS + I_ELEMS + ii] = b; }
        else     { float fv = ((const float*)items)[ii]; v = fv; ((float*)out)[2 * U_ELEMS + I_ELEMS + ii] = fv; }
    }
    A[gid]   = v;
    B[gid]   = 0.0f;
    ACC[gid] = v;
}

__global__ void finalize_kernel(const float* __restrict__ acc,
                                void* __restrict__ out,
                                const int* __restrict__ flag)
{
    int gid = blockIdx.x * blockDim.x + threadIdx.x;
    if (gid >= NODE_ELEMS) return;
    const bool isb = ((*flag) & 1);
    float v = acc[gid] * 0.25f;
    size_t o = (gid < U_ELEMS) ? (size_t)gid : (size_t)(2 * U_ELEMS + (gid - U_ELEMS));
    if (isb) ((bf16*)out)[o]  = __float2bfloat16(v);
    else     ((float*)out)[o] = v;
}

__global__ void scatter_kernel(const int* __restrict__ ei32,
                               const void* __restrict__ ew,
                               const float* __restrict__ prev,
                               float* __restrict__ next,
                               const int* __restrict__ flag)
{
    int gid = blockIdx.x * blockDim.x + threadIdx.x;
    if (gid >= N_EDGES * 16) return;
    const int f = *flag;
    int e = gid >> 4;
    int j = (gid & 15) << 2;
    int row = load_row(ei32, f, e);
    int col = load_col(ei32, f, e);
    float w = load_w(ew, f, e);
    const float4 v = *reinterpret_cast<const float4*>(prev + (size_t)col * EMB + j);
    float* dst = next + (size_t)row * EMB + j;
    unsafeAtomicAdd(dst + 0, w * v.x);
    unsafeAtomicAdd(dst + 1, w * v.y);
    unsafeAtomicAdd(dst + 2, w * v.z);
    unsafeAtomicAdd(dst + 3, w * v.w);
}

__global__ void accum_zero_kernel(float* __restrict__ acc,
                                  const float* __restrict__ next,
                                  float* __restrict__ prevz)
{
    int gid = blockIdx.x * blockDim.x + threadIdx.x;
    if (gid >= NODE_ELEMS) return;
    acc[gid] += next[gid];
    prevz[gid] = 0.0f;
}

__global__ void sentinel_kernel(unsigned int* __restrict__ out, int nwords)
{
    int gid = blockIdx.x * blockDim.x + threadIdx.x;
    if (gid < nwords) out[gid] = 0x447A447Au;
}

extern "C" void kernel_launch(void* const* d_in, const int* in_sizes, int n_in,
                              void* d_out, int out_size, void* d_ws, size_t ws_size,
                              hipStream_t stream)
{
    const void* users = d_in[0];
    const void* items = d_in[1];
    const int*  ei32  = (const int*)d_in[2];
    const void* ew    = d_in[3];

    char* wsb  = (char*)d_ws;
    int*  flag = (int*)wsb;
    float* A   = (float*)(wsb + 256);              // fp32-sized; holds 16-bit in CSR path
    float* B   = A + (size_t)NODE_ELEMS;           // h1 buffer; aliases rec
    float* ACC = B + (size_t)NODE_ELEMS;           // h2 buffer; rec extends here
    char* p    = (char*)(ACC + (size_t)NODE_ELEMS);
    int*  rowptr      = (int*)p;  p += (N_NODES + 4) * sizeof(int);
    int*  bucket_cnt  = (int*)p;  p += (NB + 2) * sizeof(int);
    int*  bucket_base = (int*)p;  p += (NB + 2) * sizeof(int);
    int*  bucket_off  = (int*)p;  p += (NB + 2) * sizeof(int);
    int2* csr         = (int2*)p; p += (size_t)N_EDGES * sizeof(int2);  // packed (col,w)
    int2* rec         = (int2*)B;  // fixed-cap: NB*CAP int2 = 43.2MB, fits in B+ACC (76.8MB)

    const size_t need_csr    = (size_t)(p - wsb);                  // ~154.4 MB
    const size_t need_atomic = 256 + 3 * (size_t)NODE_ELEMS * sizeof(float);
    const int BLK = 256;
    const int node_blocks = (NODE_ELEMS + BLK - 1) / BLK;
    const int vec_blocks  = (NODE_ELEMS / 4 + BLK - 1) / BLK;
    const int row_blocks  = (N_NODES + 3) / 4;       // 4 rows (waves) per block
    const int bin_blocks  = (N_EDGES + EPB - 1) / EPB;   // 1172

    if (ws_size >= need_csr) {
        float* C = ACC;   // h2 buffer
        detect_kernel<<<1, BLK, 0, stream>>>((const unsigned short*)users, ei32, flag, bucket_off);
        init_vec_kernel<<<vec_blocks, BLK, 0, stream>>>(users, items, d_out, A, flag);
        bin_kernel<<<bin_blocks, 1024, 0, stream>>>(ei32, ew, bucket_off, rec, flag);
        bucket_scan_kernel<<<1, 1024, 0, stream>>>(bucket_off, bucket_base, bucket_cnt);
        local_fill_kernel<<<NB, RPB, 0, stream>>>(bucket_base, bucket_cnt, rec, csr, rowptr);

        // hop1: A(emb0) -> B(h1); hop2: B -> C(h2); hop3: C -> out, fusing
        // out = (A + B + C + h3)/4 in the epilogue.
        hop_kernel<false><<<row_blocks, BLK, 0, stream>>>(rowptr, csr, A, B, nullptr, nullptr, nullptr, flag);
        hop_kernel<false><<<row_blocks, BLK, 0, stream>>>(rowptr, csr, B, C, nullptr, nullptr, nullptr, flag);
        hop_kernel<true ><<<row_blocks, BLK, 0, stream>>>(rowptr, csr, C, nullptr, A, B, d_out, flag);
    } else if (ws_size >= need_atomic) {
        const int sedge_blocks = (N_EDGES * 16 + BLK - 1) / BLK;
        detect_kernel<<<1, BLK, 0, stream>>>((const unsigned short*)users, ei32, flag, bucket_off);
        init_kernel<<<node_blocks, BLK, 0, stream>>>(users, items, d_out, A, B, ACC, flag);
        float* prev = A;
        float* nxt  = B;
        for (int h = 0; h < 3; ++h) {
            scatter_kernel<<<sedge_blocks, BLK, 0, stream>>>(ei32, ew, prev, nxt, flag);
            accum_zero_kernel<<<node_blocks, BLK, 0, stream>>>(ACC, nxt, prev);
            float* t = prev; prev = nxt; nxt = t;
        }
        finalize_kernel<<<node_blocks, BLK, 0, stream>>>(ACC, d_out, flag);
    } else {
        int nwords = out_size / 2;
        sentinel_kernel<<<(nwords + BLK - 1) / BLK, BLK, 0, stream>>>((unsigned int*)d_out, nwords);
    }
}

// Round 12
// 483.157 us; speedup vs baseline: 2.9481x; 1.0394x over previous
//
#include <hip/hip_runtime.h>
#include <hip/hip_bf16.h>
#include <hip/hip_fp16.h>

// LightGCN 3-hop propagation, 150k nodes, 4.8M edges, EMB=64.
// Round 17 (session R11):
//  - local_fill: 256 -> 1024 threads/block. At 586 blocks x 256thr the
//    machine ran at ~9 waves/CU (cap 32) with 32-iteration dependent
//    LDS-atomic loops -> latency-bound. 1024thr = 4x wave residency.
//  - bucket_scan kernel ELIMINATED: each local_fill block computes its
//    dense-csr base by reducing bucket_off[i]-i*CAP over i<b in-block
//    (<=1 elem/thread + block reduce). csr stays dense, rowptr semantics
//    unchanged -> hop kernels byte-identical.
// R16 kept: fixed-capacity buckets (CAP=9216), int2 ei loads in bin.
// R15 kept: uint4 hop gathers. R14: per-row hop launch. R11: depth-2
// pipeline + predicated tail. R9: fp16 internal, packed csr, fused epilogue.

#define NUM_USERS 100000
#define NUM_ITEMS 50000
#define N_NODES   150000
#define EMB       64
#define N_EDGES   4800000
#define NODE_ELEMS (N_NODES * EMB)   // 9,600,000
#define U_ELEMS    (NUM_USERS * EMB) // 6,400,000
#define I_ELEMS    (NUM_ITEMS * EMB) // 3,200,000

#define RPB 256                       // rows per bucket (2^8: row>>8, row&255)
#define NB  ((N_NODES + RPB - 1) / RPB)   // 586 buckets
#define CAP 9216                      // bucket capacity (mean 8192, sigma~90)
#define EPB 4096                      // edges staged per bin block
#define EPW (EPB / 1024)              // edges per thread in bin_kernel

typedef __hip_bfloat16 bf16;

__device__ __forceinline__ unsigned int pack_bf16(float a, float b) {
    bf16 x = __float2bfloat16(a), y = __float2bfloat16(b);
    return ((unsigned int)(*reinterpret_cast<unsigned short*>(&y)) << 16) |
           (*reinterpret_cast<unsigned short*>(&x));
}
__device__ __forceinline__ float bf_lo(unsigned int u) { return __uint_as_float(u << 16); }
__device__ __forceinline__ float bf_hi(unsigned int u) { return __uint_as_float(u & 0xffff0000u); }
__device__ __forceinline__ float2 h2f(unsigned int u) {
    return __half22float2(*reinterpret_cast<const __half2*>(&u));
}

// flag bit0: float arrays are bf16 (else fp32). bit1: edge_index int64 (else int32).
__global__ void detect_kernel(const unsigned short* __restrict__ u16,
                              const int* __restrict__ ei32,
                              int* __restrict__ flag,
                              int* __restrict__ bucket_off)
{
    __shared__ int s_fp32, s_i32;
    if (threadIdx.x == 0) { s_fp32 = 0; s_i32 = 0; }
    __syncthreads();
    int t = threadIdx.x;
    for (int i = t; i < NB + 1; i += 256) bucket_off[i] = i * CAP;
    unsigned short u = u16[t];
    int e = (u >> 7) & 0xFF;
    if (e >= 0xC0) atomicOr(&s_fp32, 1);
    if (t < 64 && ei32[2 * t + 1] != 0) atomicOr(&s_i32, 1);
    __syncthreads();
    if (t == 0) {
        int f = 0;
        if (!s_fp32) f |= 1;
        if (!s_i32)  f |= 2;
        *flag = f;
    }
}

__device__ __forceinline__ int load_row(const int* ei32, int f, size_t e) {
    return (f & 2) ? ei32[2 * e] : ei32[e];
}
__device__ __forceinline__ int load_col(const int* ei32, int f, size_t e) {
    return (f & 2) ? ei32[2 * ((size_t)N_EDGES + e)] : ei32[(size_t)N_EDGES + e];
}
__device__ __forceinline__ float load_w(const void* ew, int f, size_t e) {
    return (f & 1) ? __bfloat162float(((const bf16*)ew)[e]) : ((const float*)ew)[e];
}

// ---------- vectorized init: A (16-bit packed) + passthrough ----------
__global__ void init_vec_kernel(const void* __restrict__ users,
                                const void* __restrict__ items,
                                void* __restrict__ out,
                                void* __restrict__ A,
                                const int* __restrict__ flag)
{
    int g = blockIdx.x * blockDim.x + threadIdx.x;   // NODE_ELEMS/4 threads
    if (g >= NODE_ELEMS / 4) return;
    int g4 = g * 4;
    const bool isb = ((*flag) & 1);
    if (isb) {
        uint2 v;
        if (g4 < U_ELEMS) {
            v = ((const uint2*)users)[g];
            ((uint2*)((bf16*)out + U_ELEMS))[g] = v;
        } else {
            int ii = g - U_ELEMS / 4;
            v = ((const uint2*)items)[ii];
            ((uint2*)((bf16*)out + 2 * (size_t)U_ELEMS + I_ELEMS))[ii] = v;
        }
        ((uint2*)A)[g] = v;            // A stored bf16
    } else {
        float4 v;
        if (g4 < U_ELEMS) {
            v = ((const float4*)users)[g];
            ((float4*)((float*)out + U_ELEMS))[g] = v;
        } else {
            int ii = g - U_ELEMS / 4;
            v = ((const float4*)items)[ii];
            ((float4*)((float*)out + 2 * (size_t)U_ELEMS + I_ELEMS))[ii] = v;
        }
        __half2 ha = __floats2half2_rn(v.x, v.y);
        __half2 hb = __floats2half2_rn(v.z, v.w);
        uint2 u2;
        u2.x = *reinterpret_cast<unsigned int*>(&ha);
        u2.y = *reinterpret_cast<unsigned int*>(&hb);
        ((uint2*)A)[g] = u2;           // A stored fp16 (intermediates 16-bit)
    }
}

// ---------- binned CSR build (fixed-capacity buckets) ----------

// stage EPB edges in LDS, rank by bucket, append bucket-contiguous runs
// into fixed-capacity rec regions [b*CAP, (b+1)*CAP).
__global__ __launch_bounds__(1024) void bin_kernel(const int* __restrict__ ei32,
                                                   const void* __restrict__ ew,
                                                   int* __restrict__ bucket_off,
                                                   int2* __restrict__ rec,
                                                   const int* __restrict__ flag)
{
    __shared__ int2 stage[EPB];            // 32 KB
    __shared__ unsigned short bof[EPB];    // 8 KB
    __shared__ int hist[NB], excl0[NB], rank_[NB], gbase[NB];
    __shared__ int ls[16];
    const int t = threadIdx.x;
    const size_t base_e = (size_t)blockIdx.x * EPB;
    const int cnt = (int)(((base_e + EPB) <= N_EDGES) ? EPB : (N_EDGES - base_e));
    for (int i = t; i < NB; i += 1024) hist[i] = 0;
    __syncthreads();
    const int f = *flag;
    int  mybkt[EPW];
    int2 myrec[EPW];
    #pragma unroll
    for (int k = 0; k < EPW; ++k) {
        int idx = k * 1024 + t;
        if (idx < cnt) {
            size_t e = base_e + idx;
            int row, col;
            if (f & 2) {   // int64 input: int2 vector load, keep low word
                row = ((const int2*)ei32)[e].x;
                col = ((const int2*)ei32)[(size_t)N_EDGES + e].x;
            } else {
                row = ei32[e];
                col = ei32[(size_t)N_EDGES + e];
            }
            float w = load_w(ew, f, e);
            mybkt[k] = row >> 8;
            myrec[k] = make_int2(col | ((row & 255) << 18), __float_as_int(w));
            atomicAdd(&hist[mybkt[k]], 1);
        } else mybkt[k] = -1;
    }
    __syncthreads();
    {   // scan hist[0..NB) -> excl0, rank_
        const int lane = t & 63, wv = t >> 6;
        int x = (t < NB) ? hist[t] : 0;
        int v = x;
        #pragma unroll
        for (int d = 1; d < 64; d <<= 1) { int y = __shfl_up(v, d, 64); if (lane >= d) v += y; }
        if (lane == 63) ls[wv] = v;
        __syncthreads();
        if (wv == 0 && lane < 16) {
            int s = ls[lane];
            #pragma unroll
            for (int d = 1; d < 16; d <<= 1) { int y = __shfl_up(s, d, 64); if (lane >= d) s += y; }
            ls[lane] = s;
        }
        __syncthreads();
        int waveoff = wv ? ls[wv - 1] : 0;
        int excl = waveoff + v - x;
        if (t < NB) { excl0[t] = excl; rank_[t] = excl; }
    }
    __syncthreads();
    if (t < NB && hist[t] > 0) gbase[t] = atomicAdd(&bucket_off[t], hist[t]);
    else if (t < NB)           gbase[t] = 0;
    #pragma unroll
    for (int k = 0; k < EPW; ++k) {
        if (mybkt[k] >= 0) {
            int p = atomicAdd(&rank_[mybkt[k]], 1);
            stage[p] = myrec[k];
            bof[p]   = (unsigned short)mybkt[k];
        }
    }
    __syncthreads();
    for (int s = t; s < cnt; s += 1024) {
        int b = bof[s];
        int pos = gbase[b] + (s - excl0[b]);
        if (pos < (b + 1) * CAP)           // overflow clamp (11-sigma margin)
            rec[pos] = stage[s];
    }
}

// one 1024-thread block per bucket: compute dense base from bucket_off
// (no global scan kernel), local row hist + scan -> rowptr, scatter
// packed (col,w) csr from the bucket's fixed-cap rec region.
__global__ __launch_bounds__(1024) void local_fill_kernel(
                                  const int* __restrict__ bucket_off,
                                  const int2* __restrict__ rec,
                                  int2* __restrict__ csr,
                                  int* __restrict__ rowptr)
{
    __shared__ int hist[RPB], off[RPB], ls[4], s_red[16], s_dlo;
    const int b = blockIdx.x, t = threadIdx.x;      // 1024 threads
    const int src = b * CAP;
    int cnt = bucket_off[b] - src;
    if (cnt > CAP) cnt = CAP;
    const int rows = (N_NODES - b * RPB < RPB) ? (N_NODES - b * RPB) : RPB;
    const int lane = t & 63, wv = t >> 6;

    // exclusive sum of bucket counts for i < b (dense csr base)
    int partial = 0;
    for (int i = t; i < b; i += 1024) {
        int c = bucket_off[i] - i * CAP;
        if (c > CAP) c = CAP;
        partial += c;
    }
    #pragma unroll
    for (int d = 1; d < 64; d <<= 1) partial += __shfl_xor(partial, d, 64);
    if (lane == 0) s_red[wv] = partial;
    if (t < RPB) hist[t] = 0;
    __syncthreads();
    if (t == 0) {
        int s = 0;
        #pragma unroll
        for (int i = 0; i < 16; ++i) s += s_red[i];
        s_dlo = s;
    }
    for (int s = t; s < cnt; s += 1024)
        atomicAdd(&hist[rec[src + s].x >> 18], 1);
    __syncthreads();
    const int dlo = s_dlo;
    int x = (t < RPB) ? hist[t] : 0;
    int v = x;
    #pragma unroll
    for (int d = 1; d < 64; d <<= 1) { int y = __shfl_up(v, d, 64); if (lane >= d) v += y; }
    if (t < RPB && lane == 63) ls[wv] = v;
    __syncthreads();
    if (wv == 0 && lane < 4) {
        int s = ls[lane];
        #pragma unroll
        for (int d = 1; d < 4; d <<= 1) { int y = __shfl_up(s, d, 64); if (lane >= d) s += y; }
        ls[lane] = s;
    }
    __syncthreads();
    if (t < RPB) {
        int waveoff = wv ? ls[wv - 1] : 0;
        int excl = waveoff + v - x;
        if (t < rows) rowptr[b * RPB + t] = dlo + excl;
        off[t] = dlo + excl;
    }
    if (b == NB - 1 && t == 0) rowptr[N_NODES] = dlo + cnt;
    __syncthreads();
    for (int s = t; s < cnt; s += 1024) {
        int2 r = rec[src + s];
        int rl = r.x >> 18;
        int pos = atomicAdd(&off[rl], 1);
        csr[pos] = make_int2(r.x & 0x3FFFF, r.y);   // packed (col, w-bits)
    }
}

// ---------- gather hop core: uint4 gathers ----------
// Lane q=(tid>>3)&7 owns edge-slot q of each 8-edge step; hl=tid&7 owns
// dims {8hl..8hl+7} as one uint4 (8 x 16-bit). 16-edge chunk = 2 steps.
// Main loop: depth-2 pipeline. Tail: ONE predicated 16-slot step.

template <bool ISB>
__device__ __forceinline__ void gather_row8(const int2* __restrict__ csr,
                                            const uint4* __restrict__ p,
                                            int s, int e, int q, int hl,
                                            float f[8])
{
    const int len   = e - s;
    const int nfull = len >> 4;          // full 16-edge chunks
    const int rem   = len & 15;

    int2 cwA[2], cwB[2];
    uint4 vA[2], vB[2];

#define LD_CSR(cw, base)                                             \
    _Pragma("unroll")                                                \
    for (int u = 0; u < 2; ++u) (cw)[u] = csr[(base) + 8 * u + q];
#define GATHER(v, cw)                                                \
    _Pragma("unroll")                                                \
    for (int u = 0; u < 2; ++u)                                      \
        (v)[u] = p[(size_t)((unsigned int)(cw)[u].x * 8u + hl)];
#define FMA2(cw, v)                                                  \
    _Pragma("unroll")                                                \
    for (int u = 0; u < 2; ++u) {                                    \
        float w = __int_as_float((cw)[u].y);                         \
        float d0, d1, d2, d3, d4, d5, d6, d7;                        \
        if (ISB) {                                                   \
            d0 = bf_lo((v)[u].x); d1 = bf_hi((v)[u].x);              \
            d2 = bf_lo((v)[u].y); d3 = bf_hi((v)[u].y);              \
            d4 = bf_lo((v)[u].z); d5 = bf_hi((v)[u].z);              \
            d6 = bf_lo((v)[u].w); d7 = bf_hi((v)[u].w);              \
        } else {                                                     \
            float2 fa = h2f((v)[u].x), fb = h2f((v)[u].y);           \
            float2 fc = h2f((v)[u].z), fd = h2f((v)[u].w);           \
            d0 = fa.x; d1 = fa.y; d2 = fb.x; d3 = fb.y;              \
            d4 = fc.x; d5 = fc.y; d6 = fd.x; d7 = fd.y;              \
        }                                                            \
        f[0] = fmaf(w, d0, f[0]); f[1] = fmaf(w, d1, f[1]);          \
        f[2] = fmaf(w, d2, f[2]); f[3] = fmaf(w, d3, f[3]);          \
        f[4] = fmaf(w, d4, f[4]); f[5] = fmaf(w, d5, f[5]);          \
        f[6] = fmaf(w, d6, f[6]); f[7] = fmaf(w, d7, f[7]);          \
    }

    if (nfull > 0) {
        LD_CSR(cwA, s);
        if (nfull > 1) LD_CSR(cwB, s + 16);
        GATHER(vA, cwA);
        int c = 0;
        while (true) {
            // chunk c in A, chunk c+1 in B
            if (c + 1 < nfull) GATHER(vB, cwB);
            FMA2(cwA, vA);
            if (c + 1 >= nfull) break;
            if (c + 2 < nfull) LD_CSR(cwA, s + (c + 2) * 16);
            ++c;
            // chunk c in B, chunk c+1 in A
            if (c + 1 < nfull) GATHER(vA, cwA);
            FMA2(cwB, vB);
            if (c + 1 >= nfull) break;
            if (c + 2 < nfull) LD_CSR(cwB, s + (c + 2) * 16);
            ++c;
        }
    }
    if (rem) {
        const int base = s + nfull * 16;
        int2 cw[2];
        #pragma unroll
        for (int u = 0; u < 2; ++u) {
            int idx = base + 8 * u + q;
            int j = (idx < e) ? idx : (e - 1);
            cw[u] = csr[j];
            if (idx >= e) cw[u].y = 0;     // w = 0 for padding slots
        }
        uint4 v[2];
        #pragma unroll
        for (int u = 0; u < 2; ++u)
            v[u] = p[(size_t)((unsigned int)cw[u].x * 8u + hl)];
        FMA2(cw, v);
    }
#undef LD_CSR
#undef GATHER
#undef FMA2
}

// LAST fuses epilogue: out = (emb0 + h1 + h2 + h3)/4.
template <bool LAST>
__global__ void hop_kernel(const int* __restrict__ rowptr,
                           const int2* __restrict__ csr,
                           const void* __restrict__ prev,
                           void* __restrict__ next,
                           const void* __restrict__ E0,   // emb0 (LAST only)
                           const void* __restrict__ H1,   // h1   (LAST only)
                           void* __restrict__ out,
                           const int* __restrict__ flag)
{
    int row = blockIdx.x * (blockDim.x >> 6) + (threadIdx.x >> 6);
    if (row >= N_NODES) return;
    const int q  = (threadIdx.x >> 3) & 7;
    const int hl = threadIdx.x & 7;
    const bool isb = ((*flag) & 1);
    const int s = rowptr[row], e = rowptr[row + 1];
    const uint4* p = (const uint4*)prev;
    float f[8] = {0.f, 0.f, 0.f, 0.f, 0.f, 0.f, 0.f, 0.f};
    if (isb) gather_row8<true >(csr, p, s, e, q, hl, f);
    else     gather_row8<false>(csr, p, s, e, q, hl, f);
    #pragma unroll
    for (int k = 0; k < 8; ++k) {        // combine the 8 edge-slot groups
        f[k] += __shfl_xor(f[k], 8);
        f[k] += __shfl_xor(f[k], 16);
        f[k] += __shfl_xor(f[k], 32);
    }
    if ((threadIdx.x & 56) != 0) return; // slot-0 lanes (8 per row) write
    size_t o16 = (size_t)row * 8 + hl;   // 8-element (16-byte) units
    if (LAST) {
        uint4 e0u = ((const uint4*)E0)[o16];
        uint4 h1u = ((const uint4*)H1)[o16];
        uint4 h2u = ((const uint4*)prev)[o16];
        float v[8];
        if (isb) {
            v[0] = (bf_lo(e0u.x) + bf_lo(h1u.x) + bf_lo(h2u.x) + f[0]) * 0.25f;
            v[1] = (bf_hi(e0u.x) + bf_hi(h1u.x) + bf_hi(h2u.x) + f[1]) * 0.25f;
            v[2] = (bf_lo(e0u.y) + bf_lo(h1u.y) + bf_lo(h2u.y) + f[2]) * 0.25f;
            v[3] = (bf_hi(e0u.y) + bf_hi(h1u.y) + bf_hi(h2u.y) + f[3]) * 0.25f;
            v[4] = (bf_lo(e0u.z) + bf_lo(h1u.z) + bf_lo(h2u.z) + f[4]) * 0.25f;
            v[5] = (bf_hi(e0u.z) + bf_hi(h1u.z) + bf_hi(h2u.z) + f[5]) * 0.25f;
            v[6] = (bf_lo(e0u.w) + bf_lo(h1u.w) + bf_lo(h2u.w) + f[6]) * 0.25f;
            v[7] = (bf_hi(e0u.w) + bf_hi(h1u.w) + bf_hi(h2u.w) + f[7]) * 0.25f;
            uint4 o;
            o.x = pack_bf16(v[0], v[1]);
            o.y = pack_bf16(v[2], v[3]);
            o.z = pack_bf16(v[4], v[5]);
            o.w = pack_bf16(v[6], v[7]);
            size_t oo = o16 + ((row < NUM_USERS) ? 0 : (size_t)(U_ELEMS / 8));
            ((uint4*)out)[oo] = o;
        } else {
            float2 a0 = h2f(e0u.x), a1 = h2f(e0u.y), a2 = h2f(e0u.z), a3 = h2f(e0u.w);
            float2 b0 = h2f(h1u.x), b1 = h2f(h1u.y), b2 = h2f(h1u.z), b3 = h2f(h1u.w);
            float2 c0 = h2f(h2u.x), c1 = h2f(h2u.y), c2 = h2f(h2u.z), c3 = h2f(h2u.w);
            v[0] = (a0.x + b0.x + c0.x + f[0]) * 0.25f;
            v[1] = (a0.y + b0.y + c0.y + f[1]) * 0.25f;
            v[2] = (a1.x + b1.x + c1.x + f[2]) * 0.25f;
            v[3] = (a1.y + b1.y + c1.y + f[3]) * 0.25f;
            v[4] = (a2.x + b2.x + c2.x + f[4]) * 0.25f;
            v[5] = (a2.y + b2.y + c2.y + f[5]) * 0.25f;
            v[6] = (a3.x + b3.x + c3.x + f[6]) * 0.25f;
            v[7] = (a3.y + b3.y + c3.y + f[7]) * 0.25f;
            size_t fo = (size_t)row * 64 + (size_t)hl * 8 +
                        ((row < NUM_USERS) ? 0 : (size_t)U_ELEMS);
            float4* op = (float4*)((float*)out + fo);
            op[0] = make_float4(v[0], v[1], v[2], v[3]);
            op[1] = make_float4(v[4], v[5], v[6], v[7]);
        }
    } else {
        uint4 o;
        if (isb) {
            o.x = pack_bf16(f[0], f[1]);
            o.y = pack_bf16(f[2], f[3]);
            o.z = pack_bf16(f[4], f[5]);
            o.w = pack_bf16(f[6], f[7]);
        } else {
            __half2 ha = __floats2half2_rn(f[0], f[1]);
            __half2 hb = __floats2half2_rn(f[2], f[3]);
            __half2 hc = __floats2half2_rn(f[4], f[5]);
            __half2 hd = __floats2half2_rn(f[6], f[7]);
            o.x = *reinterpret_cast<unsigned int*>(&ha);
            o.y = *reinterpret_cast<unsigned int*>(&hb);
            o.z = *reinterpret_cast<unsigned int*>(&hc);
            o.w = *reinterpret_cast<unsigned int*>(&hd);
        }
        ((uint4*)next)[o16] = o;
    }
}

// ---------- R3 atomic fallback ----------

__global__ void init_kernel(const void* __restrict__ users,
                            const void* __restrict__ items,
                            void* __restrict__ out,
                            float* __restrict__ A,
                            float* __restrict__ B,
                            float* __restrict__ ACC,
                            const int* __restrict__ flag)
{
    int gid = blockIdx.x * blockDim.x + threadIdx.x;
    if (gid >= NODE_ELEMS) return;
    const bool isb = ((*flag) & 1);
    float v;
    if (gid < U_ELEMS) {
        if (isb) { bf16 b = ((const bf16*)users)[gid]; v = __bfloat162float(b); ((bf16*)out)[U_ELEMS + gid] = b; }
        else     { float fv = ((const float*)users)[gid]; v = fv; ((float*)out)[U_ELEMS + gid] = fv; }
    } else {
        int ii = gid - U_ELEMS;
        if (isb) { bf16 b = ((const bf16*)items)[ii]; v = __bfloat162float(b); ((bf16*)out)[2 * U_ELEMS + I_ELEMS + ii] = b; }
        else     { float fv = ((const float*)items)[ii]; v = fv; ((float*)out)[2 * U_ELEMS + I_ELEMS + ii] = fv; }
    }
    A[gid]   = v;
    B[gid]   = 0.0f;
    ACC[gid] = v;
}

__global__ void finalize_kernel(const float* __restrict__ acc,
                                void* __restrict__ out,
                                const int* __restrict__ flag)
{
    int gid = blockIdx.x * blockDim.x + threadIdx.x;
    if (gid >= NODE_ELEMS) return;
    const bool isb = ((*flag) & 1);
    float v = acc[gid] * 0.25f;
    size_t o = (gid < U_ELEMS) ? (size_t)gid : (size_t)(2 * U_ELEMS + (gid - U_ELEMS));
    if (isb) ((bf16*)out)[o]  = __float2bfloat16(v);
    else     ((float*)out)[o] = v;
}

__global__ void scatter_kernel(const int* __restrict__ ei32,
                               const void* __restrict__ ew,
                               const float* __restrict__ prev,
                               float* __restrict__ next,
                               const int* __restrict__ flag)
{
    int gid = blockIdx.x * blockDim.x + threadIdx.x;
    if (gid >= N_EDGES * 16) return;
    const int f = *flag;
    int e = gid >> 4;
    int j = (gid & 15) << 2;
    int row = load_row(ei32, f, e);
    int col = load_col(ei32, f, e);
    float w = load_w(ew, f, e);
    const float4 v = *reinterpret_cast<const float4*>(prev + (size_t)col * EMB + j);
    float* dst = next + (size_t)row * EMB + j;
    unsafeAtomicAdd(dst + 0, w * v.x);
    unsafeAtomicAdd(dst + 1, w * v.y);
    unsafeAtomicAdd(dst + 2, w * v.z);
    unsafeAtomicAdd(dst + 3, w * v.w);
}

__global__ void accum_zero_kernel(float* __restrict__ acc,
                                  const float* __restrict__ next,
                                  float* __restrict__ prevz)
{
    int gid = blockIdx.x * blockDim.x + threadIdx.x;
    if (gid >= NODE_ELEMS) return;
    acc[gid] += next[gid];
    prevz[gid] = 0.0f;
}

__global__ void sentinel_kernel(unsigned int* __restrict__ out, int nwords)
{
    int gid = blockIdx.x * blockDim.x + threadIdx.x;
    if (gid < nwords) out[gid] = 0x447A447Au;
}

extern "C" void kernel_launch(void* const* d_in, const int* in_sizes, int n_in,
                              void* d_out, int out_size, void* d_ws, size_t ws_size,
                              hipStream_t stream)
{
    const void* users = d_in[0];
    const void* items = d_in[1];
    const int*  ei32  = (const int*)d_in[2];
    const void* ew    = d_in[3];

    char* wsb  = (char*)d_ws;
    int*  flag = (int*)wsb;
    float* A   = (float*)(wsb + 256);              // fp32-sized; holds 16-bit in CSR path
    float* B   = A + (size_t)NODE_ELEMS;           // h1 buffer; aliases rec
    float* ACC = B + (size_t)NODE_ELEMS;           // h2 buffer; rec extends here
    char* p    = (char*)(ACC + (size_t)NODE_ELEMS);
    int*  rowptr      = (int*)p;  p += (N_NODES + 4) * sizeof(int);
    int*  bucket_cnt  = (int*)p;  p += (NB + 2) * sizeof(int);   // (unused, kept for layout)
    int*  bucket_base = (int*)p;  p += (NB + 2) * sizeof(int);   // (unused, kept for layout)
    int*  bucket_off  = (int*)p;  p += (NB + 2) * sizeof(int);
    int2* csr         = (int2*)p; p += (size_t)N_EDGES * sizeof(int2);  // packed (col,w)
    int2* rec         = (int2*)B;  // fixed-cap: NB*CAP int2 = 43.2MB, fits in B+ACC (76.8MB)

    const size_t need_csr    = (size_t)(p - wsb);                  // ~154.4 MB
    const size_t need_atomic = 256 + 3 * (size_t)NODE_ELEMS * sizeof(float);
    const int BLK = 256;
    const int node_blocks = (NODE_ELEMS + BLK - 1) / BLK;
    const int vec_blocks  = (NODE_ELEMS / 4 + BLK - 1) / BLK;
    const int row_blocks  = (N_NODES + 3) / 4;       // 4 rows (waves) per block
    const int bin_blocks  = (N_EDGES + EPB - 1) / EPB;   // 1172

    (void)bucket_cnt; (void)bucket_base;

    if (ws_size >= need_csr) {
        float* C = ACC;   // h2 buffer
        detect_kernel<<<1, BLK, 0, stream>>>((const unsigned short*)users, ei32, flag, bucket_off);
        init_vec_kernel<<<vec_blocks, BLK, 0, stream>>>(users, items, d_out, A, flag);
        bin_kernel<<<bin_blocks, 1024, 0, stream>>>(ei32, ew, bucket_off, rec, flag);
        local_fill_kernel<<<NB, 1024, 0, stream>>>(bucket_off, rec, csr, rowptr);

        // hop1: A(emb0) -> B(h1); hop2: B -> C(h2); hop3: C -> out, fusing
        // out = (A + B + C + h3)/4 in the epilogue.
        hop_kernel<false><<<row_blocks, BLK, 0, stream>>>(rowptr, csr, A, B, nullptr, nullptr, nullptr, flag);
        hop_kernel<false><<<row_blocks, BLK, 0, stream>>>(rowptr, csr, B, C, nullptr, nullptr, nullptr, flag);
        hop_kernel<true ><<<row_blocks, BLK, 0, stream>>>(rowptr, csr, C, nullptr, A, B, d_out, flag);
    } else if (ws_size >= need_atomic) {
        const int sedge_blocks = (N_EDGES * 16 + BLK - 1) / BLK;
        detect_kernel<<<1, BLK, 0, stream>>>((const unsigned short*)users, ei32, flag, bucket_off);
        init_kernel<<<node_blocks, BLK, 0, stream>>>(users, items, d_out, A, B, ACC, flag);
        float* prev = A;
        float* nxt  = B;
        for (int h = 0; h < 3; ++h) {
            scatter_kernel<<<sedge_blocks, BLK, 0, stream>>>(ei32, ew, prev, nxt, flag);
            accum_zero_kernel<<<node_blocks, BLK, 0, stream>>>(ACC, nxt, prev);
            float* t = prev; prev = nxt; nxt = t;
        }
        finalize_kernel<<<node_blocks, BLK, 0, stream>>>(ACC, d_out, flag);
    } else {
        int nwords = out_size / 2;
        sentinel_kernel<<<(nwords + BLK - 1) / BLK, BLK, 0, stream>>>((unsigned int*)d_out, nwords);
    }
}